// Round 20
// baseline (356.618 us; speedup 1.0000x reference)
//
#include <hip/hip_runtime.h>
#include <cstddef>

// Problem constants (fixed by the reference setup)
constexpr int NN = 100000;          // nodes
constexpr int NE = 1600000;         // edges (without self loops)
constexpr int TE = NE + NN;         // edges + self loops = 1,700,000
constexpr int NG = 64;              // graphs
constexpr float EPS = 1e-5f;
constexpr float NEG_SLOPE = 0.2f;
constexpr int NREP = 64;            // BN partial-sum replicas

// CSR bucket sort parameters
constexpr int NBUCK = 256;          // dst buckets
constexpr int DPB = 391;            // dsts per bucket (256*391 >= NN)
constexpr int PHB = 256;            // edge-chunk blocks
constexpr int CH = (TE + PHB - 1) / PHB;   // edges per chunk

typedef __attribute__((ext_vector_type(8))) short bf16x8;
typedef __attribute__((ext_vector_type(4))) float f32x4;

// bf16 helpers (RNE pack, exact unpack)
__device__ __forceinline__ unsigned short f2bf(float f) {
    unsigned u = __float_as_uint(f);
    u += 0x7fffu + ((u >> 16) & 1u);
    return (unsigned short)(u >> 16);
}
__device__ __forceinline__ float bf2f(unsigned short s) {
    return __uint_as_float((unsigned)s << 16);
}
__device__ __forceinline__ float bflo(unsigned u) { return __uint_as_float(u << 16); }
__device__ __forceinline__ float bfhi(unsigned u) { return __uint_as_float(u & 0xffff0000u); }
__device__ __forceinline__ void unpack8(uint4 v, float* f) {
    f[0] = bflo(v.x); f[1] = bfhi(v.x); f[2] = bflo(v.y); f[3] = bfhi(v.y);
    f[4] = bflo(v.z); f[5] = bfhi(v.z); f[6] = bflo(v.w); f[7] = bfhi(v.w);
}
__device__ __forceinline__ uint4 pack8(const float* o) {
    uint4 pk;
    pk.x = (unsigned)f2bf(o[0]) | ((unsigned)f2bf(o[1]) << 16);
    pk.y = (unsigned)f2bf(o[2]) | ((unsigned)f2bf(o[3]) << 16);
    pk.z = (unsigned)f2bf(o[4]) | ((unsigned)f2bf(o[5]) << 16);
    pk.w = (unsigned)f2bf(o[6]) | ((unsigned)f2bf(o[7]) << 16);
    return pk;
}
__device__ __forceinline__ bf16x8 ld_bf8(const unsigned short* p) {
    union { uint4 u; bf16x8 b; } cv;
    cv.u = *(const uint4*)p;
    return cv.b;
}
__device__ __forceinline__ float lrelu(float v) { return v > 0.f ? v : NEG_SLOPE * v; }

// ---------------- CSR build: bucketed counting sort ----------------

__global__ void k_hist(const int* __restrict__ ei, int* __restrict__ hist) {
    __shared__ int hcnt[NBUCK];
    for (int i = threadIdx.x; i < NBUCK; i += 256) hcnt[i] = 0;
    __syncthreads();
    int k = blockIdx.x;
    int e0 = k * CH, e1 = min(e0 + CH, TE);
    for (int e = e0 + threadIdx.x; e < e1; e += 256) {
        int d = (e < NE) ? ei[NE + e] : (e - NE);
        atomicAdd(&hcnt[d / DPB], 1);
    }
    __syncthreads();
    for (int b = threadIdx.x; b < NBUCK; b += 256) hist[b * PHB + k] = hcnt[b];
}

__global__ void k_scanA(int* __restrict__ hist, int* __restrict__ bsum) {
    __shared__ int ls[PHB];
    int b = blockIdx.x, t = threadIdx.x;
    int v = hist[b * PHB + t];
    ls[t] = v;
    __syncthreads();
    for (int off = 1; off < PHB; off <<= 1) {
        int add = (t >= off) ? ls[t - off] : 0;
        __syncthreads();
        ls[t] += add;
        __syncthreads();
    }
    hist[b * PHB + t] = ls[t] - v;      // exclusive
    if (t == PHB - 1) bsum[b] = ls[t];  // bucket total
}

__global__ void k_scanB(const int* __restrict__ bsum, int* __restrict__ bbase,
                        int* __restrict__ rowptr) {
    __shared__ int ls[NBUCK];
    int t = threadIdx.x;
    int v = bsum[t];
    ls[t] = v;
    __syncthreads();
    for (int off = 1; off < NBUCK; off <<= 1) {
        int add = (t >= off) ? ls[t - off] : 0;
        __syncthreads();
        ls[t] += add;
        __syncthreads();
    }
    bbase[t] = ls[t] - v;
    if (t == NBUCK - 1) { bbase[NBUCK] = ls[t]; rowptr[NN] = ls[t]; }  // == TE
}

__global__ void k_scatter(const int* __restrict__ ei, const int* __restrict__ hist,
                          const int* __restrict__ bbase, int* __restrict__ pairs) {
    __shared__ int cur[NBUCK];
    int k = blockIdx.x;
    for (int b = threadIdx.x; b < NBUCK; b += 256) cur[b] = bbase[b] + hist[b * PHB + k];
    __syncthreads();
    int e0 = k * CH, e1 = min(e0 + CH, TE);
    for (int e = e0 + threadIdx.x; e < e1; e += 256) {
        int s, d;
        if (e < NE) { s = ei[e]; d = ei[NE + e]; } else { s = e - NE; d = s; }
        int b = d / DPB, ld = d - b * DPB;
        int pos = atomicAdd(&cur[b], 1);
        pairs[pos] = (s << 9) | ld;
    }
}

__global__ void k_csr(const int* __restrict__ pairs, const int* __restrict__ bbase,
                      int* __restrict__ rowptr, int* __restrict__ colsrc) {
    __shared__ int deg[DPB];
    __shared__ int exc[DPB];
    __shared__ int sc[512];
    int b = blockIdx.x, t = threadIdx.x;
    int base = bbase[b], cnt = bbase[b + 1] - base;
    int d0 = b * DPB;
    int ndst = min(DPB, NN - d0);
    for (int i = t; i < DPB; i += 256) deg[i] = 0;
    __syncthreads();
    for (int i = t; i < cnt; i += 256) atomicAdd(&deg[pairs[base + i] & 511], 1);
    __syncthreads();
    sc[t] = (t < DPB) ? deg[t] : 0;
    sc[t + 256] = (t + 256 < DPB) ? deg[t + 256] : 0;
    __syncthreads();
    for (int off = 1; off < 512; off <<= 1) {
        int a0 = (t >= off) ? sc[t - off] : 0;
        int a1 = (t + 256 >= off) ? sc[t + 256 - off] : 0;
        __syncthreads();
        sc[t] += a0; sc[t + 256] += a1;
        __syncthreads();
    }
    if (t < DPB) exc[t] = sc[t] - deg[t];
    if (t + 256 < DPB) exc[t + 256] = sc[t + 256] - deg[t + 256];
    __syncthreads();
    for (int i = t; i < ndst; i += 256) rowptr[d0 + i] = base + exc[i];
    for (int i = t; i < DPB; i += 256) deg[i] = 0;
    __syncthreads();
    for (int i = t; i < cnt; i += 256) {
        int p = pairs[base + i];
        int ld = p & 511;
        int s = (unsigned)p >> 9;
        int pos = base + exc[ld] + atomicAdd(&deg[ld], 1);
        colsrc[pos] = s;
    }
}

// ---------------- wa precompute: wa[h][i] = sum_c W[i][h*C+c] * a[h][c] ----------------

__global__ void k_wa(const float* __restrict__ W1, const float* __restrict__ as1,
                     const float* __restrict__ ad1,
                     const float* __restrict__ W2, const float* __restrict__ as2,
                     const float* __restrict__ ad2,
                     const float* __restrict__ W3, const float* __restrict__ as3,
                     const float* __restrict__ ad3,
                     float* __restrict__ was1, float* __restrict__ wad1,
                     float* __restrict__ was2, float* __restrict__ wad2,
                     float* __restrict__ was3, float* __restrict__ wad3) {
    int t = threadIdx.x;
    if (t < 6) {         // L1: IN=3, C=16
        int h = t / 3, i = t % 3;
        float s = 0.f, d = 0.f;
        for (int c = 0; c < 16; ++c) {
            float w = W1[i * 32 + h * 16 + c];
            s += w * as1[h * 16 + c];
            d += w * ad1[h * 16 + c];
        }
        was1[t] = s; wad1[t] = d;
    }
    if (t < 64) {        // L2: IN=32, C=32
        int h = t / 32, i = t % 32;
        float s = 0.f, d = 0.f;
        for (int c = 0; c < 32; ++c) {
            float w = W2[i * 64 + h * 32 + c];
            s += w * as2[h * 32 + c];
            d += w * ad2[h * 32 + c];
        }
        was2[t] = s; wad2[t] = d;
    }
    if (t < 128) {       // L3: IN=64, C=64
        int h = t / 64, i = t % 64;
        float s = 0.f, d = 0.f;
        for (int c = 0; c < 64; ++c) {
            float w = W3[i * 128 + h * 64 + c];
            s += w * as3[h * 64 + c];
            d += w * ad3[h * 64 + c];
        }
        was3[t] = s; wad3[t] = d;
    }
}

// ---------------- W split+transpose: Wt_hi/lo[c][i] bf16 (W = hi + lo) ----------------

__global__ void k_wsplit(const float* __restrict__ W2, const float* __restrict__ W3,
                         unsigned short* __restrict__ w2hi, unsigned short* __restrict__ w2lo,
                         unsigned short* __restrict__ w3hi, unsigned short* __restrict__ w3lo) {
    int t = blockIdx.x * 256 + threadIdx.x;
    if (t < 2048) {                       // W2: IN=32, OUT=64; Wt[c][i]
        int c = t / 32, i = t % 32;
        float w = W2[i * 64 + c];
        unsigned short hi = f2bf(w);
        float lo = w - bf2f(hi);
        w2hi[c * 32 + i] = hi;
        w2lo[c * 32 + i] = f2bf(lo);
    }
    if (t < 8192) {                       // W3: IN=64, OUT=128; Wt[c][i]
        int c = t / 64, i = t % 64;
        float w = W3[i * 128 + c];
        unsigned short hi = f2bf(w);
        float lo = w - bf2f(hi);
        w3hi[c * 64 + i] = hi;
        w3lo[c * 64 + i] = f2bf(lo);
    }
}

// ---------------- Logits (layer 1 only: fp32 x, no BN) ----------------

__global__ void k_logits1(const float* __restrict__ x, const float* __restrict__ was,
                          const float* __restrict__ wad, float* __restrict__ als,
                          float* __restrict__ ald) {
    int n = blockIdx.x * 256 + threadIdx.x;
    if (n >= NN) return;
    float x0 = x[n * 3], x1 = x[n * 3 + 1], x2 = x[n * 3 + 2];
    als[n * 2 + 0] = x0 * was[0] + x1 * was[1] + x2 * was[2];
    als[n * 2 + 1] = x0 * was[3] + x1 * was[4] + x2 * was[5];
    ald[n * 2 + 0] = x0 * wad[0] + x1 * wad[1] + x2 * wad[2];
    ald[n * 2 + 1] = x0 * wad[3] + x1 * wad[4] + x2 * wad[5];
}

// ---------------- Prep: fused BN-apply + ReLU + logits ----------------

template <int IN>
__global__ void k_prep(const unsigned short* __restrict__ x,
                       const float* __restrict__ bnrep,
                       const float* __restrict__ gamma, const float* __restrict__ beta,
                       const float* __restrict__ was, const float* __restrict__ wad,
                       unsigned short* __restrict__ xbn,
                       float* __restrict__ als, float* __restrict__ ald) {
    constexpr int P = IN / 8;   // lanes per node (16B each)
    __shared__ float sbn[2 * IN];
    __shared__ float swa[4 * IN];
    if (threadIdx.x < IN) {
        int c = threadIdx.x;
        float s = 0.f, ss = 0.f;
#pragma unroll
        for (int r = 0; r < NREP; ++r) {
            s  += bnrep[r * 2 * IN + c];
            ss += bnrep[r * 2 * IN + IN + c];
        }
        float mu = s / NN;
        float var = ss / NN - mu * mu;
        float sca = gamma[c] * rsqrtf(var + EPS);
        sbn[c] = sca;
        sbn[IN + c] = beta[c] - mu * sca;
    }
    for (int i = threadIdx.x; i < 2 * IN; i += 256) {
        swa[i] = was[i];
        swa[2 * IN + i] = wad[i];
    }
    __syncthreads();
    int idx = blockIdx.x * 256 + threadIdx.x;
    int node = idx / P, pl = idx % P;
    if (node >= NN) return;
    uint4 v = *(const uint4*)&x[(size_t)node * IN + pl * 8];
    float f[8];
    unpack8(v, f);
    float s0 = 0.f, s1 = 0.f, d0 = 0.f, d1 = 0.f;
#pragma unroll
    for (int k = 0; k < 8; ++k) {
        int c = pl * 8 + k;
        float t = f[k] * sbn[c] + sbn[IN + c];
        t = t > 0.f ? t : 0.f;
        f[k] = t;
        s0 += t * swa[c];           s1 += t * swa[IN + c];
        d0 += t * swa[2 * IN + c];  d1 += t * swa[3 * IN + c];
    }
    *(uint4*)&xbn[(size_t)node * IN + pl * 8] = pack8(f);
#pragma unroll
    for (int m = 1; m < P; m <<= 1) {
        s0 += __shfl_xor(s0, m, 64); s1 += __shfl_xor(s1, m, 64);
        d0 += __shfl_xor(d0, m, 64); d1 += __shfl_xor(d1, m, 64);
    }
    if (pl == 0) {
        als[node * 2 + 0] = s0; als[node * 2 + 1] = s1;
        ald[node * 2 + 0] = d0; ald[node * 2 + 1] = d1;
    }
}

// ---------------- Alpha: normalized softmax weights per edge, both heads ----------------

__global__ void k_alpha(const int* __restrict__ rowptr, const int* __restrict__ colsrc,
                        const float* __restrict__ als, const float* __restrict__ ald,
                        float2* __restrict__ alf) {
    int wv = threadIdx.x >> 6, lane = threadIdx.x & 63;
    int hw = lane >> 5, hl = lane & 31;
    int base = ((int)blockIdx.x * 4 + wv) * 2;
    int wid = base + hw;
    bool valid = wid < NN;
    int start = 0, cnt = 0;
    float2 dv = make_float2(0.f, 0.f);
    if (valid) {
        start = rowptr[wid];
        cnt = rowptr[wid + 1] - start;
        dv = ((const float2*)ald)[wid];
    }
    int mc = max(cnt, __shfl_xor(cnt, 32, 64));

    if (mc <= 32) {
        int e = start + hl;
        bool act = valid && (hl < cnt);
        int s = act ? colsrc[e] : 0;
        float2 av = act ? ((const float2*)als)[s] : make_float2(0.f, 0.f);
        float t0 = act ? lrelu(av.x + dv.x) : -1e30f;
        float t1 = act ? lrelu(av.y + dv.y) : -1e30f;
        float m0 = t0, m1 = t1;
#pragma unroll
        for (int off = 16; off; off >>= 1) {
            m0 = fmaxf(m0, __shfl_xor(m0, off, 32));
            m1 = fmaxf(m1, __shfl_xor(m1, off, 32));
        }
        float w0 = act ? __expf(t0 - m0) : 0.f;
        float w1 = act ? __expf(t1 - m1) : 0.f;
        float den0 = w0, den1 = w1;
#pragma unroll
        for (int off = 16; off; off >>= 1) {
            den0 += __shfl_xor(den0, off, 32);
            den1 += __shfl_xor(den1, off, 32);
        }
        if (act) alf[e] = make_float2(w0 / den0, w1 / den1);
    } else {
        // rare fallback: whole wave per node
        for (int i2 = 0; i2 < 2; ++i2) {
            int w2 = base + i2;
            if (w2 >= NN) continue;
            int st = rowptr[w2], en = rowptr[w2 + 1];
            float2 dv2 = ((const float2*)ald)[w2];
            float m0 = -1e30f, m1 = -1e30f;
            for (int e = st + lane; e < en; e += 64) {
                int s = colsrc[e];
                m0 = fmaxf(m0, lrelu(als[s * 2 + 0] + dv2.x));
                m1 = fmaxf(m1, lrelu(als[s * 2 + 1] + dv2.y));
            }
#pragma unroll
            for (int off = 32; off; off >>= 1) {
                m0 = fmaxf(m0, __shfl_xor(m0, off, 64));
                m1 = fmaxf(m1, __shfl_xor(m1, off, 64));
            }
            float den0 = 0.f, den1 = 0.f;
            for (int e = st + lane; e < en; e += 64) {
                int s = colsrc[e];
                den0 += __expf(lrelu(als[s * 2 + 0] + dv2.x) - m0);
                den1 += __expf(lrelu(als[s * 2 + 1] + dv2.y) - m1);
            }
#pragma unroll
            for (int off = 32; off; off >>= 1) {
                den0 += __shfl_xor(den0, off, 64);
                den1 += __shfl_xor(den1, off, 64);
            }
            float inv0 = 1.f / den0, inv1 = 1.f / den1;
            for (int e = st + lane; e < en; e += 64) {
                int s = colsrc[e];
                alf[e] = make_float2(__expf(lrelu(als[s * 2 + 0] + dv2.x) - m0) * inv0,
                                     __expf(lrelu(als[s * 2 + 1] + dv2.y) - m1) * inv1);
            }
        }
    }
}

// ---------------- Gather: agg[dst][head][i] = sum alpha_e xbn[src][i] ----------------

template <int IN>
__global__ void k_gather(const int* __restrict__ rowptr, const int* __restrict__ colsrc,
                         const float2* __restrict__ alf,
                         const unsigned short* __restrict__ x,
                         unsigned short* __restrict__ agg) {
    constexpr int LPE = IN / 8;     // lanes per edge (16B each)
    constexpr int EPI2 = 32 / LPE;  // edge slots per iter per half-wave
    constexpr int UNR = 2;
    int wv = threadIdx.x >> 6, lane = threadIdx.x & 63;
    int hw = lane >> 5, hl = lane & 31;
    int wid = ((int)blockIdx.x * 4 + wv) * 2 + hw;
    if (wid >= NN) return;
    int start = rowptr[wid];
    int cnt = rowptr[wid + 1] - start;
    int sub = hl / LPE, cl = hl % LPE;
    float a0[8], a1[8];
#pragma unroll
    for (int k = 0; k < 8; ++k) { a0[k] = 0.f; a1[k] = 0.f; }
    int cm1 = cnt - 1;
    for (int j0 = 0; j0 < cnt; j0 += EPI2 * UNR) {
        float l0[UNR], l1[UNR];
        uint4 hv[UNR];
#pragma unroll
        for (int u = 0; u < UNR; ++u) {
            int jj = j0 + u * EPI2 + sub;
            int jc = min(jj, cm1);
            int e = start + jc;
            int s = colsrc[e];
            float2 al = alf[e];
            bool on = jj <= cm1;
            l0[u] = on ? al.x : 0.f;
            l1[u] = on ? al.y : 0.f;
            hv[u] = *(const uint4*)&x[(size_t)s * IN + cl * 8];
        }
#pragma unroll
        for (int u = 0; u < UNR; ++u) {
            float f[8];
            unpack8(hv[u], f);
#pragma unroll
            for (int k = 0; k < 8; ++k) {
                a0[k] += l0[u] * f[k];
                a1[k] += l1[u] * f[k];
            }
        }
    }
#pragma unroll
    for (int m = LPE; m < 32; m <<= 1) {
#pragma unroll
        for (int k = 0; k < 8; ++k) {
            a0[k] += __shfl_xor(a0[k], m, 64);
            a1[k] += __shfl_xor(a1[k], m, 64);
        }
    }
    if (sub == 0) {
        *(uint4*)&agg[(size_t)wid * 2 * IN + cl * 8] = pack8(a0);
        *(uint4*)&agg[(size_t)wid * 2 * IN + IN + cl * 8] = pack8(a1);
    }
}

// Layer-1 aggregate: x fp32 [NN][3] (1.2 MB, L2-resident); agg fp32 [NN][6].
__global__ void k_agg1(const int* __restrict__ rowptr, const int* __restrict__ colsrc,
                       const float* __restrict__ x, const float* __restrict__ als,
                       const float* __restrict__ ald, float* __restrict__ agg) {
    int wv = threadIdx.x >> 6, lane = threadIdx.x & 63;
    int hw = lane >> 5, hl = lane & 31;
    int base = ((int)blockIdx.x * 4 + wv) * 2;
    int wid = base + hw;
    bool valid = wid < NN;
    int start = 0, cnt = 0;
    float2 dv = make_float2(0.f, 0.f);
    if (valid) {
        start = rowptr[wid];
        cnt = rowptr[wid + 1] - start;
        dv = ((const float2*)ald)[wid];
    }
    int mc = max(cnt, __shfl_xor(cnt, 32, 64));
    if (mc <= 32) {
        int e = start + hl;
        bool act = valid && (hl < cnt);
        int s = act ? colsrc[e] : 0;
        float2 av = act ? ((const float2*)als)[s] : make_float2(0.f, 0.f);
        float t0 = act ? lrelu(av.x + dv.x) : -1e30f;
        float t1 = act ? lrelu(av.y + dv.y) : -1e30f;
        float m0 = t0, m1 = t1;
#pragma unroll
        for (int off = 16; off; off >>= 1) {
            m0 = fmaxf(m0, __shfl_xor(m0, off, 32));
            m1 = fmaxf(m1, __shfl_xor(m1, off, 32));
        }
        float w0 = act ? __expf(t0 - m0) : 0.f;
        float w1 = act ? __expf(t1 - m1) : 0.f;
        float den0 = w0, den1 = w1;
#pragma unroll
        for (int off = 16; off; off >>= 1) {
            den0 += __shfl_xor(den0, off, 32);
            den1 += __shfl_xor(den1, off, 32);
        }
        float a[6];
#pragma unroll
        for (int k = 0; k < 6; ++k) a[k] = 0.f;
        if (act) {
            float al0 = w0 / den0, al1 = w1 / den1;
            float x0 = x[s * 3], x1 = x[s * 3 + 1], x2 = x[s * 3 + 2];
            a[0] = al0 * x0; a[1] = al0 * x1; a[2] = al0 * x2;
            a[3] = al1 * x0; a[4] = al1 * x1; a[5] = al1 * x2;
        }
#pragma unroll
        for (int m = 1; m < 32; m <<= 1) {
#pragma unroll
            for (int k = 0; k < 6; ++k) a[k] += __shfl_xor(a[k], m, 64);
        }
        if (valid && hl == 0) {
#pragma unroll
            for (int k = 0; k < 6; ++k) agg[(size_t)wid * 6 + k] = a[k];
        }
    } else {
        for (int i2 = 0; i2 < 2; ++i2) {
            int w2 = base + i2;
            if (w2 >= NN) continue;
            int st = rowptr[w2], en = rowptr[w2 + 1];
            float2 dv2 = ((const float2*)ald)[w2];
            float m0 = -1e30f, m1 = -1e30f;
            for (int e = st + lane; e < en; e += 64) {
                int s = colsrc[e];
                m0 = fmaxf(m0, lrelu(als[s * 2 + 0] + dv2.x));
                m1 = fmaxf(m1, lrelu(als[s * 2 + 1] + dv2.y));
            }
#pragma unroll
            for (int off = 32; off; off >>= 1) {
                m0 = fmaxf(m0, __shfl_xor(m0, off, 64));
                m1 = fmaxf(m1, __shfl_xor(m1, off, 64));
            }
            float den0 = 0.f, den1 = 0.f;
            for (int e = st + lane; e < en; e += 64) {
                int s = colsrc[e];
                den0 += __expf(lrelu(als[s * 2 + 0] + dv2.x) - m0);
                den1 += __expf(lrelu(als[s * 2 + 1] + dv2.y) - m1);
            }
#pragma unroll
            for (int off = 32; off; off >>= 1) {
                den0 += __shfl_xor(den0, off, 64);
                den1 += __shfl_xor(den1, off, 64);
            }
            float inv0 = 1.f / den0, inv1 = 1.f / den1;
            float a[6];
#pragma unroll
            for (int k = 0; k < 6; ++k) a[k] = 0.f;
            for (int e = st + lane; e < en; e += 64) {
                int s = colsrc[e];
                float aa0 = __expf(lrelu(als[s * 2 + 0] + dv2.x) - m0) * inv0;
                float aa1 = __expf(lrelu(als[s * 2 + 1] + dv2.y) - m1) * inv1;
                float x0 = x[s * 3], x1 = x[s * 3 + 1], x2 = x[s * 3 + 2];
                a[0] += aa0 * x0; a[1] += aa0 * x1; a[2] += aa0 * x2;
                a[3] += aa1 * x0; a[4] += aa1 * x1; a[5] += aa1 * x2;
            }
#pragma unroll
            for (int m = 1; m < 64; m <<= 1) {
#pragma unroll
                for (int k = 0; k < 6; ++k) a[k] += __shfl_xor(a[k], m, 64);
            }
            if (lane == 0) {
#pragma unroll
                for (int k = 0; k < 6; ++k) agg[(size_t)w2 * 6 + k] = a[k];
            }
        }
    }
}

// ---------------- MFMA transform (per-head GEMM, error-split bf16 W) ----------------
// Epilogue stages bf16 D-values through padded LDS, then writes full coalesced
// uint4 rows (replaces 16 scattered 2B stores per lane).

template <int IN, int OUT>
__global__ void k_tmfma(const unsigned short* __restrict__ agg,
                        const unsigned short* __restrict__ whi,
                        const unsigned short* __restrict__ wlo,
                        unsigned short* __restrict__ xout,
                        float* __restrict__ bnrep) {
    constexpr int C = OUT / 2;
    constexpr int NT = C / 16;      // n-tiles per head
    constexpr int KS = IN / 32;     // k-steps
    constexpr int RP = OUT + 8;     // padded LDS row stride (ushorts)
    __shared__ __align__(16) unsigned short xsm[32 * RP];
    __shared__ float red[2 * OUT];
    for (int i = threadIdx.x; i < 2 * OUT; i += 256) red[i] = 0.f;
    __syncthreads();
    int wv = threadIdx.x >> 6, l = threadIdx.x & 63;
    int head = wv & 1;
    int nrow0 = (wv >> 1) * 16;           // local node row base (0 or 16)
    int nodeB = blockIdx.x * 32;
    int lr = l & 15, kg = l >> 4;
    bf16x8 a[KS];
#pragma unroll
    for (int ks = 0; ks < KS; ++ks)
        a[ks] = ld_bf8(&agg[(size_t)(nodeB + nrow0 + lr) * 2 * IN + head * IN + ks * 32 + kg * 8]);
    f32x4 acc[NT];
#pragma unroll
    for (int nt = 0; nt < NT; ++nt) acc[nt] = (f32x4){0.f, 0.f, 0.f, 0.f};
#pragma unroll
    for (int nt = 0; nt < NT; ++nt) {
        int ch = head * C + nt * 16 + lr;          // B col for this lane
#pragma unroll
        for (int ks = 0; ks < KS; ++ks) {
            bf16x8 bh = ld_bf8(&whi[(size_t)ch * IN + ks * 32 + kg * 8]);
            bf16x8 bl = ld_bf8(&wlo[(size_t)ch * IN + ks * 32 + kg * 8]);
            acc[nt] = __builtin_amdgcn_mfma_f32_16x16x32_bf16(a[ks], bh, acc[nt], 0, 0, 0);
            acc[nt] = __builtin_amdgcn_mfma_f32_16x16x32_bf16(a[ks], bl, acc[nt], 0, 0, 0);
        }
    }
    // epilogue: D col = l&15 (channel), row = kg*4 + r (node); stage into LDS
#pragma unroll
    for (int nt = 0; nt < NT; ++nt) {
        int chO = head * C + nt * 16 + lr;
        float s = 0.f, ss = 0.f;
#pragma unroll
        for (int r = 0; r < 4; ++r) {
            float v = acc[nt][r];
            xsm[(nrow0 + kg * 4 + r) * RP + chO] = f2bf(v);
            s += v; ss += v * v;
        }
        atomicAdd(&red[chO], s);
        atomicAdd(&red[OUT + chO], ss);
    }
    __syncthreads();
    // coalesced write: 32 rows x OUT ushorts as uint4
    constexpr int NV = 32 * OUT / 8;
    for (int i = threadIdx.x; i < NV; i += 256) {
        int row = i / (OUT / 8), c8 = i % (OUT / 8);
        uint4 v = *(const uint4*)&xsm[row * RP + c8 * 8];
        *(uint4*)&xout[(size_t)(nodeB + row) * OUT + c8 * 8] = v;
    }
    float* dst = &bnrep[(blockIdx.x & (NREP - 1)) * 2 * OUT];
    for (int i = threadIdx.x; i < 2 * OUT; i += 256) atomicAdd(&dst[i], red[i]);
}

// Layer-1 transform: agg fp32 [NN][6] -> out [NN][32] bf16 + BN1 partials.
__global__ void k_transform1(const float* __restrict__ agg, const float* __restrict__ W,
                             unsigned short* __restrict__ xout, float* __restrict__ bnrep,
                             int n) {
    __shared__ float xs[32 * 7];     // padded node stride 7 (6 used)
    __shared__ float red[64];
    for (int i = threadIdx.x; i < 64; i += 256) red[i] = 0.f;
    int node0 = blockIdx.x * 32;
    for (int i = threadIdx.x; i < 192; i += 256) {
        int nn = node0 + i / 6;
        float v = (nn < n) ? agg[(size_t)node0 * 6 + i] : 0.f;
        xs[(i / 6) * 7 + (i % 6)] = v;
    }
    __syncthreads();
    int nl = threadIdx.x / 8, q = threadIdx.x % 8;
    int hd = (q >= 4);
    int node = node0 + nl;
    float4 acc = {0.f, 0.f, 0.f, 0.f};
#pragma unroll
    for (int i = 0; i < 3; ++i) {
        float xv = xs[nl * 7 + hd * 3 + i];
        float4 w = *(const float4*)&W[i * 32 + q * 4];
        acc.x += xv * w.x; acc.y += xv * w.y; acc.z += xv * w.z; acc.w += xv * w.w;
    }
    if (node < n) {
        uint2 pk;
        pk.x = (unsigned)f2bf(acc.x) | ((unsigned)f2bf(acc.y) << 16);
        pk.y = (unsigned)f2bf(acc.z) | ((unsigned)f2bf(acc.w) << 16);
        *(uint2*)&xout[(size_t)node * 32 + q * 4] = pk;
        atomicAdd(&red[q * 4 + 0], acc.x); atomicAdd(&red[32 + q * 4 + 0], acc.x * acc.x);
        atomicAdd(&red[q * 4 + 1], acc.y); atomicAdd(&red[32 + q * 4 + 1], acc.y * acc.y);
        atomicAdd(&red[q * 4 + 2], acc.z); atomicAdd(&red[32 + q * 4 + 2], acc.z * acc.z);
        atomicAdd(&red[q * 4 + 3], acc.w); atomicAdd(&red[32 + q * 4 + 3], acc.w * acc.w);
    }
    __syncthreads();
    float* dst = &bnrep[(blockIdx.x & (NREP - 1)) * 64];
    for (int i = threadIdx.x; i < 64; i += 256) atomicAdd(&dst[i], red[i]);
}

// ---------------- Pooling (BN3 inline + ReLU) + FC ----------------

__global__ void k_pool(const unsigned short* __restrict__ h, const int* __restrict__ batch,
                       const float* __restrict__ bnrep, const float* __restrict__ gamma,
                       const float* __restrict__ beta, float* __restrict__ pooled, int n) {
    const int K = 32;
    int c = threadIdx.x;
    float s = 0.f, ss = 0.f;
#pragma unroll
    for (int r = 0; r < NREP; ++r) {
        s  += bnrep[r * 256 + c];
        ss += bnrep[r * 256 + 128 + c];
    }
    float mu = s / n;
    float var = ss / n - mu * mu;
    float scale = gamma[c] * rsqrtf(var + EPS);
    float shift = beta[c] - mu * scale;
    int n0 = blockIdx.x * K;
    if (n0 >= n) return;
    int nend = min(n, n0 + K);
    int curg = batch[n0];
    float m = 0.f;
    for (int nn = n0; nn < nend; ++nn) {
        int g = batch[nn];
        if (g != curg) {
            atomicMax((int*)&pooled[curg * 128 + c], __float_as_int(m));
            m = 0.f; curg = g;
        }
        float v = bf2f(h[(size_t)nn * 128 + c]) * scale + shift;
        m = fmaxf(m, v > 0.f ? v : 0.f);
    }
    atomicMax((int*)&pooled[curg * 128 + c], __float_as_int(m));
}

__global__ void k_fc(const float* __restrict__ pooled, const float* __restrict__ fcw,
                     const float* __restrict__ fcb, float* __restrict__ out) {
    int t = threadIdx.x;
    if (t >= NG * 10) return;
    int g = t / 10, j = t % 10;
    float acc = fcb[j];
#pragma unroll
    for (int c = 0; c < 128; ++c) acc += pooled[g * 128 + c] * fcw[c * 10 + j];
    out[g * 10 + j] = acc;
}

// ---------------- Host launch ----------------

extern "C" void kernel_launch(void* const* d_in, const int* in_sizes, int n_in,
                              void* d_out, int out_size, void* d_ws, size_t ws_size,
                              hipStream_t stream) {
    const float* x   = (const float*)d_in[0];
    const int*   ei  = (const int*)d_in[1];
    const int*   bat = (const int*)d_in[2];
    const float* W1  = (const float*)d_in[3];
    const float* as1 = (const float*)d_in[4];
    const float* ad1 = (const float*)d_in[5];
    // d_in[6] = b1 (cancels under BN)
    const float* g1  = (const float*)d_in[7];
    const float* be1 = (const float*)d_in[8];
    const float* W2  = (const float*)d_in[9];
    const float* as2 = (const float*)d_in[10];
    const float* ad2 = (const float*)d_in[11];
    const float* g2  = (const float*)d_in[13];
    const float* be2 = (const float*)d_in[14];
    const float* W3  = (const float*)d_in[15];
    const float* as3 = (const float*)d_in[16];
    const float* ad3 = (const float*)d_in[17];
    const float* g3  = (const float*)d_in[19];
    const float* be3 = (const float*)d_in[20];
    const float* fcw = (const float*)d_in[21];
    const float* fcb = (const float*)d_in[22];
    float* out = (float*)d_out;

    char* w = (char*)d_ws;
    size_t off = 0;
    auto take = [&](size_t bytes) {
        void* p = w + off;
        off += (bytes + 255) & ~(size_t)255;
        return p;
    };
    // ---- single zero-init region: bnrep1/2/3 | pooled ----
    constexpr size_t ZN = (size_t)NREP * 2 * (32 + 64 + 128) + NG * 128;
    char* zreg = (char*)take(ZN * 4);
    float* bnr1   = (float*)zreg;                    // NREP*64
    float* bnr2   = bnr1 + NREP * 64;                // NREP*128
    float* bnr3   = bnr2 + NREP * 128;               // NREP*256
    float* pooled = bnr3 + NREP * 256;               // NG*128

    int*   hist    = (int*)take((size_t)NBUCK * PHB * 4);
    int*   bsum    = (int*)take(NBUCK * 4);
    int*   bbase   = (int*)take((NBUCK + 1) * 4);
    int*   rowptr  = (int*)take((size_t)(NN + 1) * 4);
    int*   pairs   = (int*)take((size_t)TE * 4);
    int*   colsrc  = (int*)take((size_t)TE * 4);
    float* al_s    = (float*)take((size_t)NN * 2 * 4);
    float* al_d    = (float*)take((size_t)NN * 2 * 4);
    float2* alf    = (float2*)take((size_t)TE * 8);
    float* was1    = (float*)take(64);
    float* wad1    = (float*)take(64);
    float* was2    = (float*)take(64 * 4);
    float* wad2    = (float*)take(64 * 4);
    float* was3    = (float*)take(128 * 4);
    float* wad3    = (float*)take(128 * 4);
    unsigned short* w2hi = (unsigned short*)take(2048 * 2);
    unsigned short* w2lo = (unsigned short*)take(2048 * 2);
    unsigned short* w3hi = (unsigned short*)take(8192 * 2);
    unsigned short* w3lo = (unsigned short*)take(8192 * 2);
    float* agg1f   = (float*)take((size_t)NN * 6 * 4);                  // fp32 [NN][6]
    unsigned short* aggb = (unsigned short*)take((size_t)NN * 128 * 2); // bf16 [NN][2*IN]
    unsigned short* x2   = (unsigned short*)take((size_t)NN * 32 * 2);  // pre-BN
    unsigned short* xbn2 = (unsigned short*)take((size_t)NN * 32 * 2);  // post-BN-ReLU
    unsigned short* x3   = (unsigned short*)take((size_t)NN * 64 * 2);
    unsigned short* xbn3 = (unsigned short*)take((size_t)NN * 64 * 2);
    unsigned short* x4   = (unsigned short*)take((size_t)NN * 128 * 2);

    hipMemsetAsync(zreg, 0, ZN * 4, stream);

    // ---- CSR build (bucketed counting sort) ----
    k_hist<<<PHB, 256, 0, stream>>>(ei, hist);
    k_scanA<<<NBUCK, PHB, 0, stream>>>(hist, bsum);
    k_scanB<<<1, NBUCK, 0, stream>>>(bsum, bbase, rowptr);
    k_scatter<<<PHB, 256, 0, stream>>>(ei, hist, bbase, pairs);
    k_csr<<<NBUCK, 256, 0, stream>>>(pairs, bbase, rowptr, colsrc);

    k_wa<<<1, 256, 0, stream>>>(W1, as1, ad1, W2, as2, ad2, W3, as3, ad3,
                                was1, wad1, was2, wad2, was3, wad3);
    k_wsplit<<<32, 256, 0, stream>>>(W2, W3, w2hi, w2lo, w3hi, w3lo);

    const int AGG_BLOCKS = (NN + 7) / 8;   // 4 waves/block, 2 nodes/wave

    // ---- layer 1: 3 -> 32 ----
    k_logits1<<<(NN + 255) / 256, 256, 0, stream>>>(x, was1, wad1, al_s, al_d);
    k_agg1<<<AGG_BLOCKS, 256, 0, stream>>>(rowptr, colsrc, x, al_s, al_d, agg1f);
    k_transform1<<<(NN + 31) / 32, 256, 0, stream>>>(agg1f, W1, x2, bnr1, NN);

    // ---- layer 2: 32 -> 64 ----
    k_prep<32><<<(NN * 4 + 255) / 256, 256, 0, stream>>>(x2, bnr1, g1, be1, was2, wad2,
                                                         xbn2, al_s, al_d);
    k_alpha<<<AGG_BLOCKS, 256, 0, stream>>>(rowptr, colsrc, al_s, al_d, alf);
    k_gather<32><<<AGG_BLOCKS, 256, 0, stream>>>(rowptr, colsrc, alf, xbn2, aggb);
    k_tmfma<32, 64><<<NN / 32, 256, 0, stream>>>(aggb, w2hi, w2lo, x3, bnr2);

    // ---- layer 3: 64 -> 128 ----
    k_prep<64><<<(NN * 8 + 255) / 256, 256, 0, stream>>>(x3, bnr2, g2, be2, was3, wad3,
                                                         xbn3, al_s, al_d);
    k_alpha<<<AGG_BLOCKS, 256, 0, stream>>>(rowptr, colsrc, al_s, al_d, alf);
    k_gather<64><<<AGG_BLOCKS, 256, 0, stream>>>(rowptr, colsrc, alf, xbn3, aggb);
    k_tmfma<64, 128><<<NN / 32, 256, 0, stream>>>(aggb, w3hi, w3lo, x4, bnr3);

    // ---- pool (BN3 inline) + fc ----
    k_pool<<<(NN + 31) / 32, 128, 0, stream>>>(x4, bat, bnr3, g3, be3, pooled, NN);
    k_fc<<<1, 640, 0, stream>>>(pooled, fcw, fcb, out);
}

// Round 21
// 337.997 us; speedup vs baseline: 1.0551x; 1.0551x over previous
//
#include <hip/hip_runtime.h>
#include <cstddef>

// Problem constants (fixed by the reference setup)
constexpr int NN = 100000;          // nodes
constexpr int NE = 1600000;         // edges (without self loops)
constexpr int TE = NE + NN;         // edges + self loops = 1,700,000
constexpr int NG = 64;              // graphs
constexpr float EPS = 1e-5f;
constexpr float NEG_SLOPE = 0.2f;
constexpr int NREP = 8;             // BN partial-sum replicas (XCD-aligned: bid&7)

// CSR bucket sort parameters
constexpr int NBUCK = 256;          // dst buckets
constexpr int DPB = 391;            // dsts per bucket (256*391 >= NN)
constexpr int PHB = 256;            // edge-chunk blocks
constexpr int CH = (TE + PHB - 1) / PHB;   // edges per chunk

typedef __attribute__((ext_vector_type(8))) short bf16x8;
typedef __attribute__((ext_vector_type(4))) float f32x4;

// bf16 helpers (RNE pack, exact unpack)
__device__ __forceinline__ unsigned short f2bf(float f) {
    unsigned u = __float_as_uint(f);
    u += 0x7fffu + ((u >> 16) & 1u);
    return (unsigned short)(u >> 16);
}
__device__ __forceinline__ float bf2f(unsigned short s) {
    return __uint_as_float((unsigned)s << 16);
}
__device__ __forceinline__ float bflo(unsigned u) { return __uint_as_float(u << 16); }
__device__ __forceinline__ float bfhi(unsigned u) { return __uint_as_float(u & 0xffff0000u); }
__device__ __forceinline__ void unpack8(uint4 v, float* f) {
    f[0] = bflo(v.x); f[1] = bfhi(v.x); f[2] = bflo(v.y); f[3] = bfhi(v.y);
    f[4] = bflo(v.z); f[5] = bfhi(v.z); f[6] = bflo(v.w); f[7] = bfhi(v.w);
}
__device__ __forceinline__ uint4 pack8(const float* o) {
    uint4 pk;
    pk.x = (unsigned)f2bf(o[0]) | ((unsigned)f2bf(o[1]) << 16);
    pk.y = (unsigned)f2bf(o[2]) | ((unsigned)f2bf(o[3]) << 16);
    pk.z = (unsigned)f2bf(o[4]) | ((unsigned)f2bf(o[5]) << 16);
    pk.w = (unsigned)f2bf(o[6]) | ((unsigned)f2bf(o[7]) << 16);
    return pk;
}
__device__ __forceinline__ bf16x8 ld_bf8(const unsigned short* p) {
    union { uint4 u; bf16x8 b; } cv;
    cv.u = *(const uint4*)p;
    return cv.b;
}
__device__ __forceinline__ float lrelu(float v) { return v > 0.f ? v : NEG_SLOPE * v; }

// ---------------- CSR build: bucketed counting sort ----------------

__global__ void k_hist(const int* __restrict__ ei, int* __restrict__ hist) {
    __shared__ int hcnt[NBUCK];
    for (int i = threadIdx.x; i < NBUCK; i += 256) hcnt[i] = 0;
    __syncthreads();
    int k = blockIdx.x;
    int e0 = k * CH, e1 = min(e0 + CH, TE);
    for (int e = e0 + threadIdx.x; e < e1; e += 256) {
        int d = (e < NE) ? ei[NE + e] : (e - NE);
        atomicAdd(&hcnt[d / DPB], 1);
    }
    __syncthreads();
    for (int b = threadIdx.x; b < NBUCK; b += 256) hist[b * PHB + k] = hcnt[b];
}

__global__ void k_scanA(int* __restrict__ hist, int* __restrict__ bsum) {
    __shared__ int ls[PHB];
    int b = blockIdx.x, t = threadIdx.x;
    int v = hist[b * PHB + t];
    ls[t] = v;
    __syncthreads();
    for (int off = 1; off < PHB; off <<= 1) {
        int add = (t >= off) ? ls[t - off] : 0;
        __syncthreads();
        ls[t] += add;
        __syncthreads();
    }
    hist[b * PHB + t] = ls[t] - v;      // exclusive
    if (t == PHB - 1) bsum[b] = ls[t];  // bucket total
}

__global__ void k_scanB(const int* __restrict__ bsum, int* __restrict__ bbase,
                        int* __restrict__ rowptr) {
    __shared__ int ls[NBUCK];
    int t = threadIdx.x;
    int v = bsum[t];
    ls[t] = v;
    __syncthreads();
    for (int off = 1; off < NBUCK; off <<= 1) {
        int add = (t >= off) ? ls[t - off] : 0;
        __syncthreads();
        ls[t] += add;
        __syncthreads();
    }
    bbase[t] = ls[t] - v;
    if (t == NBUCK - 1) { bbase[NBUCK] = ls[t]; rowptr[NN] = ls[t]; }  // == TE
}

__global__ void k_scatter(const int* __restrict__ ei, const int* __restrict__ hist,
                          const int* __restrict__ bbase, int* __restrict__ pairs) {
    __shared__ int cur[NBUCK];
    int k = blockIdx.x;
    for (int b = threadIdx.x; b < NBUCK; b += 256) cur[b] = bbase[b] + hist[b * PHB + k];
    __syncthreads();
    int e0 = k * CH, e1 = min(e0 + CH, TE);
    for (int e = e0 + threadIdx.x; e < e1; e += 256) {
        int s, d;
        if (e < NE) { s = ei[e]; d = ei[NE + e]; } else { s = e - NE; d = s; }
        int b = d / DPB, ld = d - b * DPB;
        int pos = atomicAdd(&cur[b], 1);
        pairs[pos] = (s << 9) | ld;
    }
}

__global__ void k_csr(const int* __restrict__ pairs, const int* __restrict__ bbase,
                      int* __restrict__ rowptr, int* __restrict__ colsrc) {
    __shared__ int deg[DPB];
    __shared__ int exc[DPB];
    __shared__ int sc[512];
    int b = blockIdx.x, t = threadIdx.x;
    int base = bbase[b], cnt = bbase[b + 1] - base;
    int d0 = b * DPB;
    int ndst = min(DPB, NN - d0);
    for (int i = t; i < DPB; i += 256) deg[i] = 0;
    __syncthreads();
    for (int i = t; i < cnt; i += 256) atomicAdd(&deg[pairs[base + i] & 511], 1);
    __syncthreads();
    sc[t] = (t < DPB) ? deg[t] : 0;
    sc[t + 256] = (t + 256 < DPB) ? deg[t + 256] : 0;
    __syncthreads();
    for (int off = 1; off < 512; off <<= 1) {
        int a0 = (t >= off) ? sc[t - off] : 0;
        int a1 = (t + 256 >= off) ? sc[t + 256 - off] : 0;
        __syncthreads();
        sc[t] += a0; sc[t + 256] += a1;
        __syncthreads();
    }
    if (t < DPB) exc[t] = sc[t] - deg[t];
    if (t + 256 < DPB) exc[t + 256] = sc[t + 256] - deg[t + 256];
    __syncthreads();
    for (int i = t; i < ndst; i += 256) rowptr[d0 + i] = base + exc[i];
    for (int i = t; i < DPB; i += 256) deg[i] = 0;
    __syncthreads();
    for (int i = t; i < cnt; i += 256) {
        int p = pairs[base + i];
        int ld = p & 511;
        int s = (unsigned)p >> 9;
        int pos = base + exc[ld] + atomicAdd(&deg[ld], 1);
        colsrc[pos] = s;
    }
}

// ---------------- wa precompute: wa[h][i] = sum_c W[i][h*C+c] * a[h][c] ----------------

__global__ void k_wa(const float* __restrict__ W1, const float* __restrict__ as1,
                     const float* __restrict__ ad1,
                     const float* __restrict__ W2, const float* __restrict__ as2,
                     const float* __restrict__ ad2,
                     const float* __restrict__ W3, const float* __restrict__ as3,
                     const float* __restrict__ ad3,
                     float* __restrict__ was1, float* __restrict__ wad1,
                     float* __restrict__ was2, float* __restrict__ wad2,
                     float* __restrict__ was3, float* __restrict__ wad3) {
    int t = threadIdx.x;
    if (t < 6) {         // L1: IN=3, C=16
        int h = t / 3, i = t % 3;
        float s = 0.f, d = 0.f;
        for (int c = 0; c < 16; ++c) {
            float w = W1[i * 32 + h * 16 + c];
            s += w * as1[h * 16 + c];
            d += w * ad1[h * 16 + c];
        }
        was1[t] = s; wad1[t] = d;
    }
    if (t < 64) {        // L2: IN=32, C=32
        int h = t / 32, i = t % 32;
        float s = 0.f, d = 0.f;
        for (int c = 0; c < 32; ++c) {
            float w = W2[i * 64 + h * 32 + c];
            s += w * as2[h * 32 + c];
            d += w * ad2[h * 32 + c];
        }
        was2[t] = s; wad2[t] = d;
    }
    if (t < 128) {       // L3: IN=64, C=64
        int h = t / 64, i = t % 64;
        float s = 0.f, d = 0.f;
        for (int c = 0; c < 64; ++c) {
            float w = W3[i * 128 + h * 64 + c];
            s += w * as3[h * 64 + c];
            d += w * ad3[h * 64 + c];
        }
        was3[t] = s; wad3[t] = d;
    }
}

// ---------------- W split+transpose: Wt_hi/lo[c][i] bf16 (W = hi + lo) ----------------

__global__ void k_wsplit(const float* __restrict__ W2, const float* __restrict__ W3,
                         unsigned short* __restrict__ w2hi, unsigned short* __restrict__ w2lo,
                         unsigned short* __restrict__ w3hi, unsigned short* __restrict__ w3lo) {
    int t = blockIdx.x * 256 + threadIdx.x;
    if (t < 2048) {                       // W2: IN=32, OUT=64; Wt[c][i]
        int c = t / 32, i = t % 32;
        float w = W2[i * 64 + c];
        unsigned short hi = f2bf(w);
        float lo = w - bf2f(hi);
        w2hi[c * 32 + i] = hi;
        w2lo[c * 32 + i] = f2bf(lo);
    }
    if (t < 8192) {                       // W3: IN=64, OUT=128; Wt[c][i]
        int c = t / 64, i = t % 64;
        float w = W3[i * 128 + c];
        unsigned short hi = f2bf(w);
        float lo = w - bf2f(hi);
        w3hi[c * 64 + i] = hi;
        w3lo[c * 64 + i] = f2bf(lo);
    }
}

// ---------------- Logits (layer 1 only: fp32 x, no BN) ----------------

__global__ void k_logits1(const float* __restrict__ x, const float* __restrict__ was,
                          const float* __restrict__ wad, float* __restrict__ als,
                          float* __restrict__ ald) {
    int n = blockIdx.x * 256 + threadIdx.x;
    if (n >= NN) return;
    float x0 = x[n * 3], x1 = x[n * 3 + 1], x2 = x[n * 3 + 2];
    als[n * 2 + 0] = x0 * was[0] + x1 * was[1] + x2 * was[2];
    als[n * 2 + 1] = x0 * was[3] + x1 * was[4] + x2 * was[5];
    ald[n * 2 + 0] = x0 * wad[0] + x1 * wad[1] + x2 * wad[2];
    ald[n * 2 + 1] = x0 * wad[3] + x1 * wad[4] + x2 * wad[5];
}

// ---------------- Prep: fused BN-apply + ReLU + logits ----------------

template <int IN>
__global__ void k_prep(const unsigned short* __restrict__ x,
                       const float* __restrict__ bnrep,
                       const float* __restrict__ gamma, const float* __restrict__ beta,
                       const float* __restrict__ was, const float* __restrict__ wad,
                       unsigned short* __restrict__ xbn,
                       float* __restrict__ als, float* __restrict__ ald) {
    constexpr int P = IN / 8;   // lanes per node (16B each)
    __shared__ float sbn[2 * IN];
    __shared__ float swa[4 * IN];
    if (threadIdx.x < IN) {
        int c = threadIdx.x;
        float s = 0.f, ss = 0.f;
#pragma unroll
        for (int r = 0; r < NREP; ++r) {
            s  += bnrep[r * 2 * IN + c];
            ss += bnrep[r * 2 * IN + IN + c];
        }
        float mu = s / NN;
        float var = ss / NN - mu * mu;
        float sca = gamma[c] * rsqrtf(var + EPS);
        sbn[c] = sca;
        sbn[IN + c] = beta[c] - mu * sca;
    }
    for (int i = threadIdx.x; i < 2 * IN; i += 256) {
        swa[i] = was[i];
        swa[2 * IN + i] = wad[i];
    }
    __syncthreads();
    int idx = blockIdx.x * 256 + threadIdx.x;
    int node = idx / P, pl = idx % P;
    if (node >= NN) return;
    uint4 v = *(const uint4*)&x[(size_t)node * IN + pl * 8];
    float f[8];
    unpack8(v, f);
    float s0 = 0.f, s1 = 0.f, d0 = 0.f, d1 = 0.f;
#pragma unroll
    for (int k = 0; k < 8; ++k) {
        int c = pl * 8 + k;
        float t = f[k] * sbn[c] + sbn[IN + c];
        t = t > 0.f ? t : 0.f;
        f[k] = t;
        s0 += t * swa[c];           s1 += t * swa[IN + c];
        d0 += t * swa[2 * IN + c];  d1 += t * swa[3 * IN + c];
    }
    *(uint4*)&xbn[(size_t)node * IN + pl * 8] = pack8(f);
#pragma unroll
    for (int m = 1; m < P; m <<= 1) {
        s0 += __shfl_xor(s0, m, 64); s1 += __shfl_xor(s1, m, 64);
        d0 += __shfl_xor(d0, m, 64); d1 += __shfl_xor(d1, m, 64);
    }
    if (pl == 0) {
        als[node * 2 + 0] = s0; als[node * 2 + 1] = s1;
        ald[node * 2 + 0] = d0; ald[node * 2 + 1] = d1;
    }
}

// ---------------- Alpha: normalized softmax weights per edge, both heads ----------------

__global__ void k_alpha(const int* __restrict__ rowptr, const int* __restrict__ colsrc,
                        const float* __restrict__ als, const float* __restrict__ ald,
                        float2* __restrict__ alf) {
    int wv = threadIdx.x >> 6, lane = threadIdx.x & 63;
    int hw = lane >> 5, hl = lane & 31;
    int base = ((int)blockIdx.x * 4 + wv) * 2;
    int wid = base + hw;
    bool valid = wid < NN;
    int start = 0, cnt = 0;
    float2 dv = make_float2(0.f, 0.f);
    if (valid) {
        start = rowptr[wid];
        cnt = rowptr[wid + 1] - start;
        dv = ((const float2*)ald)[wid];
    }
    int mc = max(cnt, __shfl_xor(cnt, 32, 64));

    if (mc <= 32) {
        int e = start + hl;
        bool act = valid && (hl < cnt);
        int s = act ? colsrc[e] : 0;
        float2 av = act ? ((const float2*)als)[s] : make_float2(0.f, 0.f);
        float t0 = act ? lrelu(av.x + dv.x) : -1e30f;
        float t1 = act ? lrelu(av.y + dv.y) : -1e30f;
        float m0 = t0, m1 = t1;
#pragma unroll
        for (int off = 16; off; off >>= 1) {
            m0 = fmaxf(m0, __shfl_xor(m0, off, 32));
            m1 = fmaxf(m1, __shfl_xor(m1, off, 32));
        }
        float w0 = act ? __expf(t0 - m0) : 0.f;
        float w1 = act ? __expf(t1 - m1) : 0.f;
        float den0 = w0, den1 = w1;
#pragma unroll
        for (int off = 16; off; off >>= 1) {
            den0 += __shfl_xor(den0, off, 32);
            den1 += __shfl_xor(den1, off, 32);
        }
        if (act) alf[e] = make_float2(w0 / den0, w1 / den1);
    } else {
        // rare fallback: whole wave per node
        for (int i2 = 0; i2 < 2; ++i2) {
            int w2 = base + i2;
            if (w2 >= NN) continue;
            int st = rowptr[w2], en = rowptr[w2 + 1];
            float2 dv2 = ((const float2*)ald)[w2];
            float m0 = -1e30f, m1 = -1e30f;
            for (int e = st + lane; e < en; e += 64) {
                int s = colsrc[e];
                m0 = fmaxf(m0, lrelu(als[s * 2 + 0] + dv2.x));
                m1 = fmaxf(m1, lrelu(als[s * 2 + 1] + dv2.y));
            }
#pragma unroll
            for (int off = 32; off; off >>= 1) {
                m0 = fmaxf(m0, __shfl_xor(m0, off, 64));
                m1 = fmaxf(m1, __shfl_xor(m1, off, 64));
            }
            float den0 = 0.f, den1 = 0.f;
            for (int e = st + lane; e < en; e += 64) {
                int s = colsrc[e];
                den0 += __expf(lrelu(als[s * 2 + 0] + dv2.x) - m0);
                den1 += __expf(lrelu(als[s * 2 + 1] + dv2.y) - m1);
            }
#pragma unroll
            for (int off = 32; off; off >>= 1) {
                den0 += __shfl_xor(den0, off, 64);
                den1 += __shfl_xor(den1, off, 64);
            }
            float inv0 = 1.f / den0, inv1 = 1.f / den1;
            for (int e = st + lane; e < en; e += 64) {
                int s = colsrc[e];
                alf[e] = make_float2(__expf(lrelu(als[s * 2 + 0] + dv2.x) - m0) * inv0,
                                     __expf(lrelu(als[s * 2 + 1] + dv2.y) - m1) * inv1);
            }
        }
    }
}

// ---------------- Gather: agg[dst][head][i] = sum alpha_e xbn[src][i] ----------------

template <int IN>
__global__ void k_gather(const int* __restrict__ rowptr, const int* __restrict__ colsrc,
                         const float2* __restrict__ alf,
                         const unsigned short* __restrict__ x,
                         unsigned short* __restrict__ agg) {
    constexpr int LPE = IN / 8;     // lanes per edge (16B each)
    constexpr int EPI2 = 32 / LPE;  // edge slots per iter per half-wave
    constexpr int UNR = 2;
    int wv = threadIdx.x >> 6, lane = threadIdx.x & 63;
    int hw = lane >> 5, hl = lane & 31;
    int wid = ((int)blockIdx.x * 4 + wv) * 2 + hw;
    if (wid >= NN) return;
    int start = rowptr[wid];
    int cnt = rowptr[wid + 1] - start;
    int sub = hl / LPE, cl = hl % LPE;
    float a0[8], a1[8];
#pragma unroll
    for (int k = 0; k < 8; ++k) { a0[k] = 0.f; a1[k] = 0.f; }
    int cm1 = cnt - 1;
    for (int j0 = 0; j0 < cnt; j0 += EPI2 * UNR) {
        float l0[UNR], l1[UNR];
        uint4 hv[UNR];
#pragma unroll
        for (int u = 0; u < UNR; ++u) {
            int jj = j0 + u * EPI2 + sub;
            int jc = min(jj, cm1);
            int e = start + jc;
            int s = colsrc[e];
            float2 al = alf[e];
            bool on = jj <= cm1;
            l0[u] = on ? al.x : 0.f;
            l1[u] = on ? al.y : 0.f;
            hv[u] = *(const uint4*)&x[(size_t)s * IN + cl * 8];
        }
#pragma unroll
        for (int u = 0; u < UNR; ++u) {
            float f[8];
            unpack8(hv[u], f);
#pragma unroll
            for (int k = 0; k < 8; ++k) {
                a0[k] += l0[u] * f[k];
                a1[k] += l1[u] * f[k];
            }
        }
    }
#pragma unroll
    for (int m = LPE; m < 32; m <<= 1) {
#pragma unroll
        for (int k = 0; k < 8; ++k) {
            a0[k] += __shfl_xor(a0[k], m, 64);
            a1[k] += __shfl_xor(a1[k], m, 64);
        }
    }
    if (sub == 0) {
        *(uint4*)&agg[(size_t)wid * 2 * IN + cl * 8] = pack8(a0);
        *(uint4*)&agg[(size_t)wid * 2 * IN + IN + cl * 8] = pack8(a1);
    }
}

// Layer-1 aggregate: x fp32 [NN][3] (1.2 MB, L2-resident); agg fp32 [NN][6].
__global__ void k_agg1(const int* __restrict__ rowptr, const int* __restrict__ colsrc,
                       const float* __restrict__ x, const float* __restrict__ als,
                       const float* __restrict__ ald, float* __restrict__ agg) {
    int wv = threadIdx.x >> 6, lane = threadIdx.x & 63;
    int hw = lane >> 5, hl = lane & 31;
    int base = ((int)blockIdx.x * 4 + wv) * 2;
    int wid = base + hw;
    bool valid = wid < NN;
    int start = 0, cnt = 0;
    float2 dv = make_float2(0.f, 0.f);
    if (valid) {
        start = rowptr[wid];
        cnt = rowptr[wid + 1] - start;
        dv = ((const float2*)ald)[wid];
    }
    int mc = max(cnt, __shfl_xor(cnt, 32, 64));
    if (mc <= 32) {
        int e = start + hl;
        bool act = valid && (hl < cnt);
        int s = act ? colsrc[e] : 0;
        float2 av = act ? ((const float2*)als)[s] : make_float2(0.f, 0.f);
        float t0 = act ? lrelu(av.x + dv.x) : -1e30f;
        float t1 = act ? lrelu(av.y + dv.y) : -1e30f;
        float m0 = t0, m1 = t1;
#pragma unroll
        for (int off = 16; off; off >>= 1) {
            m0 = fmaxf(m0, __shfl_xor(m0, off, 32));
            m1 = fmaxf(m1, __shfl_xor(m1, off, 32));
        }
        float w0 = act ? __expf(t0 - m0) : 0.f;
        float w1 = act ? __expf(t1 - m1) : 0.f;
        float den0 = w0, den1 = w1;
#pragma unroll
        for (int off = 16; off; off >>= 1) {
            den0 += __shfl_xor(den0, off, 32);
            den1 += __shfl_xor(den1, off, 32);
        }
        float a[6];
#pragma unroll
        for (int k = 0; k < 6; ++k) a[k] = 0.f;
        if (act) {
            float al0 = w0 / den0, al1 = w1 / den1;
            float x0 = x[s * 3], x1 = x[s * 3 + 1], x2 = x[s * 3 + 2];
            a[0] = al0 * x0; a[1] = al0 * x1; a[2] = al0 * x2;
            a[3] = al1 * x0; a[4] = al1 * x1; a[5] = al1 * x2;
        }
#pragma unroll
        for (int m = 1; m < 32; m <<= 1) {
#pragma unroll
            for (int k = 0; k < 6; ++k) a[k] += __shfl_xor(a[k], m, 64);
        }
        if (valid && hl == 0) {
#pragma unroll
            for (int k = 0; k < 6; ++k) agg[(size_t)wid * 6 + k] = a[k];
        }
    } else {
        for (int i2 = 0; i2 < 2; ++i2) {
            int w2 = base + i2;
            if (w2 >= NN) continue;
            int st = rowptr[w2], en = rowptr[w2 + 1];
            float2 dv2 = ((const float2*)ald)[w2];
            float m0 = -1e30f, m1 = -1e30f;
            for (int e = st + lane; e < en; e += 64) {
                int s = colsrc[e];
                m0 = fmaxf(m0, lrelu(als[s * 2 + 0] + dv2.x));
                m1 = fmaxf(m1, lrelu(als[s * 2 + 1] + dv2.y));
            }
#pragma unroll
            for (int off = 32; off; off >>= 1) {
                m0 = fmaxf(m0, __shfl_xor(m0, off, 64));
                m1 = fmaxf(m1, __shfl_xor(m1, off, 64));
            }
            float den0 = 0.f, den1 = 0.f;
            for (int e = st + lane; e < en; e += 64) {
                int s = colsrc[e];
                den0 += __expf(lrelu(als[s * 2 + 0] + dv2.x) - m0);
                den1 += __expf(lrelu(als[s * 2 + 1] + dv2.y) - m1);
            }
#pragma unroll
            for (int off = 32; off; off >>= 1) {
                den0 += __shfl_xor(den0, off, 64);
                den1 += __shfl_xor(den1, off, 64);
            }
            float inv0 = 1.f / den0, inv1 = 1.f / den1;
            float a[6];
#pragma unroll
            for (int k = 0; k < 6; ++k) a[k] = 0.f;
            for (int e = st + lane; e < en; e += 64) {
                int s = colsrc[e];
                float aa0 = __expf(lrelu(als[s * 2 + 0] + dv2.x) - m0) * inv0;
                float aa1 = __expf(lrelu(als[s * 2 + 1] + dv2.y) - m1) * inv1;
                float x0 = x[s * 3], x1 = x[s * 3 + 1], x2 = x[s * 3 + 2];
                a[0] += aa0 * x0; a[1] += aa0 * x1; a[2] += aa0 * x2;
                a[3] += aa1 * x0; a[4] += aa1 * x1; a[5] += aa1 * x2;
            }
#pragma unroll
            for (int m = 1; m < 64; m <<= 1) {
#pragma unroll
                for (int k = 0; k < 6; ++k) a[k] += __shfl_xor(a[k], m, 64);
            }
            if (lane == 0) {
#pragma unroll
                for (int k = 0; k < 6; ++k) agg[(size_t)w2 * 6 + k] = a[k];
            }
        }
    }
}

// ---------------- MFMA transform (per-head GEMM, error-split bf16 W) ----------------
// BN partial atomics go to the bid&7 replica: with default round-robin
// block->XCD dispatch each replica is only touched by one XCD, so the lines
// stay in that XCD's L2 (no cross-XCD migration). Performance heuristic only.

template <int IN, int OUT>
__global__ void k_tmfma(const unsigned short* __restrict__ agg,
                        const unsigned short* __restrict__ whi,
                        const unsigned short* __restrict__ wlo,
                        unsigned short* __restrict__ xout,
                        float* __restrict__ bnrep) {
    constexpr int C = OUT / 2;
    constexpr int NT = C / 16;      // n-tiles per head
    constexpr int KS = IN / 32;     // k-steps
    __shared__ float red[2 * OUT];
    for (int i = threadIdx.x; i < 2 * OUT; i += 256) red[i] = 0.f;
    __syncthreads();
    int wv = threadIdx.x >> 6, l = threadIdx.x & 63;
    int head = wv & 1;
    int node0 = blockIdx.x * 32 + (wv >> 1) * 16;
    int lr = l & 15, kg = l >> 4;
    bf16x8 a[KS];
#pragma unroll
    for (int ks = 0; ks < KS; ++ks)
        a[ks] = ld_bf8(&agg[(size_t)(node0 + lr) * 2 * IN + head * IN + ks * 32 + kg * 8]);
    f32x4 acc[NT];
#pragma unroll
    for (int nt = 0; nt < NT; ++nt) acc[nt] = (f32x4){0.f, 0.f, 0.f, 0.f};
#pragma unroll
    for (int nt = 0; nt < NT; ++nt) {
        int ch = head * C + nt * 16 + lr;          // B col for this lane
#pragma unroll
        for (int ks = 0; ks < KS; ++ks) {
            bf16x8 bh = ld_bf8(&whi[(size_t)ch * IN + ks * 32 + kg * 8]);
            bf16x8 bl = ld_bf8(&wlo[(size_t)ch * IN + ks * 32 + kg * 8]);
            acc[nt] = __builtin_amdgcn_mfma_f32_16x16x32_bf16(a[ks], bh, acc[nt], 0, 0, 0);
            acc[nt] = __builtin_amdgcn_mfma_f32_16x16x32_bf16(a[ks], bl, acc[nt], 0, 0, 0);
        }
    }
    // epilogue: D col = l&15 (channel), row = kg*4 + r (node)
#pragma unroll
    for (int nt = 0; nt < NT; ++nt) {
        int chO = head * C + nt * 16 + lr;
        float s = 0.f, ss = 0.f;
#pragma unroll
        for (int r = 0; r < 4; ++r) {
            float v = acc[nt][r];
            int node = node0 + kg * 4 + r;
            xout[(size_t)node * OUT + chO] = f2bf(v);
            s += v; ss += v * v;
        }
        atomicAdd(&red[chO], s);
        atomicAdd(&red[OUT + chO], ss);
    }
    __syncthreads();
    float* dst = &bnrep[(blockIdx.x & (NREP - 1)) * 2 * OUT];
    for (int i = threadIdx.x; i < 2 * OUT; i += 256) atomicAdd(&dst[i], red[i]);
}

// Layer-1 transform: agg fp32 [NN][6] -> out [NN][32] bf16 + BN1 partials.
__global__ void k_transform1(const float* __restrict__ agg, const float* __restrict__ W,
                             unsigned short* __restrict__ xout, float* __restrict__ bnrep,
                             int n) {
    __shared__ float xs[32 * 7];     // padded node stride 7 (6 used)
    __shared__ float red[64];
    for (int i = threadIdx.x; i < 64; i += 256) red[i] = 0.f;
    int node0 = blockIdx.x * 32;
    for (int i = threadIdx.x; i < 192; i += 256) {
        int nn = node0 + i / 6;
        float v = (nn < n) ? agg[(size_t)node0 * 6 + i] : 0.f;
        xs[(i / 6) * 7 + (i % 6)] = v;
    }
    __syncthreads();
    int nl = threadIdx.x / 8, q = threadIdx.x % 8;
    int hd = (q >= 4);
    int node = node0 + nl;
    float4 acc = {0.f, 0.f, 0.f, 0.f};
#pragma unroll
    for (int i = 0; i < 3; ++i) {
        float xv = xs[nl * 7 + hd * 3 + i];
        float4 w = *(const float4*)&W[i * 32 + q * 4];
        acc.x += xv * w.x; acc.y += xv * w.y; acc.z += xv * w.z; acc.w += xv * w.w;
    }
    __syncthreads();
    if (node < n) {
        uint2 pk;
        pk.x = (unsigned)f2bf(acc.x) | ((unsigned)f2bf(acc.y) << 16);
        pk.y = (unsigned)f2bf(acc.z) | ((unsigned)f2bf(acc.w) << 16);
        *(uint2*)&xout[(size_t)node * 32 + q * 4] = pk;
        atomicAdd(&red[q * 4 + 0], acc.x); atomicAdd(&red[32 + q * 4 + 0], acc.x * acc.x);
        atomicAdd(&red[q * 4 + 1], acc.y); atomicAdd(&red[32 + q * 4 + 1], acc.y * acc.y);
        atomicAdd(&red[q * 4 + 2], acc.z); atomicAdd(&red[32 + q * 4 + 2], acc.z * acc.z);
        atomicAdd(&red[q * 4 + 3], acc.w); atomicAdd(&red[32 + q * 4 + 3], acc.w * acc.w);
    }
    __syncthreads();
    float* dst = &bnrep[(blockIdx.x & (NREP - 1)) * 64];
    for (int i = threadIdx.x; i < 64; i += 256) atomicAdd(&dst[i], red[i]);
}

// ---------------- Pooling (BN3 inline + ReLU) + FC ----------------

__global__ void k_pool(const unsigned short* __restrict__ h, const int* __restrict__ batch,
                       const float* __restrict__ bnrep, const float* __restrict__ gamma,
                       const float* __restrict__ beta, float* __restrict__ pooled, int n) {
    const int K = 32;
    int c = threadIdx.x;
    float s = 0.f, ss = 0.f;
#pragma unroll
    for (int r = 0; r < NREP; ++r) {
        s  += bnrep[r * 256 + c];
        ss += bnrep[r * 256 + 128 + c];
    }
    float mu = s / n;
    float var = ss / n - mu * mu;
    float scale = gamma[c] * rsqrtf(var + EPS);
    float shift = beta[c] - mu * scale;
    int n0 = blockIdx.x * K;
    if (n0 >= n) return;
    int nend = min(n, n0 + K);
    int curg = batch[n0];
    float m = 0.f;
    for (int nn = n0; nn < nend; ++nn) {
        int g = batch[nn];
        if (g != curg) {
            atomicMax((int*)&pooled[curg * 128 + c], __float_as_int(m));
            m = 0.f; curg = g;
        }
        float v = bf2f(h[(size_t)nn * 128 + c]) * scale + shift;
        m = fmaxf(m, v > 0.f ? v : 0.f);
    }
    atomicMax((int*)&pooled[curg * 128 + c], __float_as_int(m));
}

__global__ void k_fc(const float* __restrict__ pooled, const float* __restrict__ fcw,
                     const float* __restrict__ fcb, float* __restrict__ out) {
    int t = threadIdx.x;
    if (t >= NG * 10) return;
    int g = t / 10, j = t % 10;
    float acc = fcb[j];
#pragma unroll
    for (int c = 0; c < 128; ++c) acc += pooled[g * 128 + c] * fcw[c * 10 + j];
    out[g * 10 + j] = acc;
}

// ---------------- Host launch ----------------

extern "C" void kernel_launch(void* const* d_in, const int* in_sizes, int n_in,
                              void* d_out, int out_size, void* d_ws, size_t ws_size,
                              hipStream_t stream) {
    const float* x   = (const float*)d_in[0];
    const int*   ei  = (const int*)d_in[1];
    const int*   bat = (const int*)d_in[2];
    const float* W1  = (const float*)d_in[3];
    const float* as1 = (const float*)d_in[4];
    const float* ad1 = (const float*)d_in[5];
    // d_in[6] = b1 (cancels under BN)
    const float* g1  = (const float*)d_in[7];
    const float* be1 = (const float*)d_in[8];
    const float* W2  = (const float*)d_in[9];
    const float* as2 = (const float*)d_in[10];
    const float* ad2 = (const float*)d_in[11];
    const float* g2  = (const float*)d_in[13];
    const float* be2 = (const float*)d_in[14];
    const float* W3  = (const float*)d_in[15];
    const float* as3 = (const float*)d_in[16];
    const float* ad3 = (const float*)d_in[17];
    const float* g3  = (const float*)d_in[19];
    const float* be3 = (const float*)d_in[20];
    const float* fcw = (const float*)d_in[21];
    const float* fcb = (const float*)d_in[22];
    float* out = (float*)d_out;

    char* w = (char*)d_ws;
    size_t off = 0;
    auto take = [&](size_t bytes) {
        void* p = w + off;
        off += (bytes + 255) & ~(size_t)255;
        return p;
    };
    // ---- single zero-init region: bnrep1/2/3 | pooled ----
    constexpr size_t ZN = (size_t)NREP * 2 * (32 + 64 + 128) + NG * 128;
    char* zreg = (char*)take(ZN * 4);
    float* bnr1   = (float*)zreg;                    // NREP*64
    float* bnr2   = bnr1 + NREP * 64;                // NREP*128
    float* bnr3   = bnr2 + NREP * 128;               // NREP*256
    float* pooled = bnr3 + NREP * 256;               // NG*128

    int*   hist    = (int*)take((size_t)NBUCK * PHB * 4);
    int*   bsum    = (int*)take(NBUCK * 4);
    int*   bbase   = (int*)take((NBUCK + 1) * 4);
    int*   rowptr  = (int*)take((size_t)(NN + 1) * 4);
    int*   pairs   = (int*)take((size_t)TE * 4);
    int*   colsrc  = (int*)take((size_t)TE * 4);
    float* al_s    = (float*)take((size_t)NN * 2 * 4);
    float* al_d    = (float*)take((size_t)NN * 2 * 4);
    float2* alf    = (float2*)take((size_t)TE * 8);
    float* was1    = (float*)take(64);
    float* wad1    = (float*)take(64);
    float* was2    = (float*)take(64 * 4);
    float* wad2    = (float*)take(64 * 4);
    float* was3    = (float*)take(128 * 4);
    float* wad3    = (float*)take(128 * 4);
    unsigned short* w2hi = (unsigned short*)take(2048 * 2);
    unsigned short* w2lo = (unsigned short*)take(2048 * 2);
    unsigned short* w3hi = (unsigned short*)take(8192 * 2);
    unsigned short* w3lo = (unsigned short*)take(8192 * 2);
    float* agg1f   = (float*)take((size_t)NN * 6 * 4);                  // fp32 [NN][6]
    unsigned short* aggb = (unsigned short*)take((size_t)NN * 128 * 2); // bf16 [NN][2*IN]
    unsigned short* x2   = (unsigned short*)take((size_t)NN * 32 * 2);  // pre-BN
    unsigned short* xbn2 = (unsigned short*)take((size_t)NN * 32 * 2);  // post-BN-ReLU
    unsigned short* x3   = (unsigned short*)take((size_t)NN * 64 * 2);
    unsigned short* xbn3 = (unsigned short*)take((size_t)NN * 64 * 2);
    unsigned short* x4   = (unsigned short*)take((size_t)NN * 128 * 2);

    hipMemsetAsync(zreg, 0, ZN * 4, stream);

    // ---- CSR build (bucketed counting sort) ----
    k_hist<<<PHB, 256, 0, stream>>>(ei, hist);
    k_scanA<<<NBUCK, PHB, 0, stream>>>(hist, bsum);
    k_scanB<<<1, NBUCK, 0, stream>>>(bsum, bbase, rowptr);
    k_scatter<<<PHB, 256, 0, stream>>>(ei, hist, bbase, pairs);
    k_csr<<<NBUCK, 256, 0, stream>>>(pairs, bbase, rowptr, colsrc);

    k_wa<<<1, 256, 0, stream>>>(W1, as1, ad1, W2, as2, ad2, W3, as3, ad3,
                                was1, wad1, was2, wad2, was3, wad3);
    k_wsplit<<<32, 256, 0, stream>>>(W2, W3, w2hi, w2lo, w3hi, w3lo);

    const int AGG_BLOCKS = (NN + 7) / 8;   // 4 waves/block, 2 nodes/wave

    // ---- layer 1: 3 -> 32 ----
    k_logits1<<<(NN + 255) / 256, 256, 0, stream>>>(x, was1, wad1, al_s, al_d);
    k_agg1<<<AGG_BLOCKS, 256, 0, stream>>>(rowptr, colsrc, x, al_s, al_d, agg1f);
    k_transform1<<<(NN + 31) / 32, 256, 0, stream>>>(agg1f, W1, x2, bnr1, NN);

    // ---- layer 2: 32 -> 64 ----
    k_prep<32><<<(NN * 4 + 255) / 256, 256, 0, stream>>>(x2, bnr1, g1, be1, was2, wad2,
                                                         xbn2, al_s, al_d);
    k_alpha<<<AGG_BLOCKS, 256, 0, stream>>>(rowptr, colsrc, al_s, al_d, alf);
    k_gather<32><<<AGG_BLOCKS, 256, 0, stream>>>(rowptr, colsrc, alf, xbn2, aggb);
    k_tmfma<32, 64><<<NN / 32, 256, 0, stream>>>(aggb, w2hi, w2lo, x3, bnr2);

    // ---- layer 3: 64 -> 128 ----
    k_prep<64><<<(NN * 8 + 255) / 256, 256, 0, stream>>>(x3, bnr2, g2, be2, was3, wad3,
                                                         xbn3, al_s, al_d);
    k_alpha<<<AGG_BLOCKS, 256, 0, stream>>>(rowptr, colsrc, al_s, al_d, alf);
    k_gather<64><<<AGG_BLOCKS, 256, 0, stream>>>(rowptr, colsrc, alf, xbn3, aggb);
    k_tmfma<64, 128><<<NN / 32, 256, 0, stream>>>(aggb, w3hi, w3lo, x4, bnr3);

    // ---- pool (BN3 inline) + fc ----
    k_pool<<<(NN + 31) / 32, 128, 0, stream>>>(x4, bat, bnr3, g3, be3, pooled, NN);
    k_fc<<<1, 640, 0, stream>>>(pooled, fcw, fcb, out);
}

// Round 22
// 321.160 us; speedup vs baseline: 1.1104x; 1.0524x over previous
//
#include <hip/hip_runtime.h>
#include <cstddef>

// Problem constants (fixed by the reference setup)
constexpr int NN = 100000;          // nodes
constexpr int NE = 1600000;         // edges (without self loops)
constexpr int TE = NE + NN;         // edges + self loops = 1,700,000
constexpr int NG = 64;              // graphs
constexpr float EPS = 1e-5f;
constexpr float NEG_SLOPE = 0.2f;
constexpr int NREP = 8;             // BN partial-sum replicas (XCD-aligned: bid&7)

// CSR bucket sort parameters
constexpr int NBUCK = 256;          // dst buckets
constexpr int DPB = 391;            // dsts per bucket (256*391 >= NN)
constexpr int PHB = 256;            // edge-chunk blocks
constexpr int CH = (TE + PHB - 1) / PHB;   // edges per chunk

typedef __attribute__((ext_vector_type(8))) short bf16x8;
typedef __attribute__((ext_vector_type(4))) float f32x4;

// bf16 helpers (RNE pack, exact unpack)
__device__ __forceinline__ unsigned short f2bf(float f) {
    unsigned u = __float_as_uint(f);
    u += 0x7fffu + ((u >> 16) & 1u);
    return (unsigned short)(u >> 16);
}
__device__ __forceinline__ float bf2f(unsigned short s) {
    return __uint_as_float((unsigned)s << 16);
}
__device__ __forceinline__ float bflo(unsigned u) { return __uint_as_float(u << 16); }
__device__ __forceinline__ float bfhi(unsigned u) { return __uint_as_float(u & 0xffff0000u); }
__device__ __forceinline__ void unpack8(uint4 v, float* f) {
    f[0] = bflo(v.x); f[1] = bfhi(v.x); f[2] = bflo(v.y); f[3] = bfhi(v.y);
    f[4] = bflo(v.z); f[5] = bfhi(v.z); f[6] = bflo(v.w); f[7] = bfhi(v.w);
}
__device__ __forceinline__ uint4 pack8(const float* o) {
    uint4 pk;
    pk.x = (unsigned)f2bf(o[0]) | ((unsigned)f2bf(o[1]) << 16);
    pk.y = (unsigned)f2bf(o[2]) | ((unsigned)f2bf(o[3]) << 16);
    pk.z = (unsigned)f2bf(o[4]) | ((unsigned)f2bf(o[5]) << 16);
    pk.w = (unsigned)f2bf(o[6]) | ((unsigned)f2bf(o[7]) << 16);
    return pk;
}
__device__ __forceinline__ bf16x8 ld_bf8(const unsigned short* p) {
    union { uint4 u; bf16x8 b; } cv;
    cv.u = *(const uint4*)p;
    return cv.b;
}
__device__ __forceinline__ float lrelu(float v) { return v > 0.f ? v : NEG_SLOPE * v; }

// ---------------- CSR build: bucketed counting sort ----------------

__global__ void k_hist(const int* __restrict__ ei, int* __restrict__ hist) {
    __shared__ int hcnt[NBUCK];
    for (int i = threadIdx.x; i < NBUCK; i += 256) hcnt[i] = 0;
    __syncthreads();
    int k = blockIdx.x;
    int e0 = k * CH, e1 = min(e0 + CH, TE);
    for (int e = e0 + threadIdx.x; e < e1; e += 256) {
        int d = (e < NE) ? ei[NE + e] : (e - NE);
        atomicAdd(&hcnt[d / DPB], 1);
    }
    __syncthreads();
    for (int b = threadIdx.x; b < NBUCK; b += 256) hist[b * PHB + k] = hcnt[b];
}

__global__ void k_scanA(int* __restrict__ hist, int* __restrict__ bsum) {
    __shared__ int ls[PHB];
    int b = blockIdx.x, t = threadIdx.x;
    int v = hist[b * PHB + t];
    ls[t] = v;
    __syncthreads();
    for (int off = 1; off < PHB; off <<= 1) {
        int add = (t >= off) ? ls[t - off] : 0;
        __syncthreads();
        ls[t] += add;
        __syncthreads();
    }
    hist[b * PHB + t] = ls[t] - v;      // exclusive
    if (t == PHB - 1) bsum[b] = ls[t];  // bucket total
}

__global__ void k_scanB(const int* __restrict__ bsum, int* __restrict__ bbase,
                        int* __restrict__ rowptr) {
    __shared__ int ls[NBUCK];
    int t = threadIdx.x;
    int v = bsum[t];
    ls[t] = v;
    __syncthreads();
    for (int off = 1; off < NBUCK; off <<= 1) {
        int add = (t >= off) ? ls[t - off] : 0;
        __syncthreads();
        ls[t] += add;
        __syncthreads();
    }
    bbase[t] = ls[t] - v;
    if (t == NBUCK - 1) { bbase[NBUCK] = ls[t]; rowptr[NN] = ls[t]; }  // == TE
}

__global__ void k_scatter(const int* __restrict__ ei, const int* __restrict__ hist,
                          const int* __restrict__ bbase, int* __restrict__ pairs) {
    __shared__ int cur[NBUCK];
    int k = blockIdx.x;
    for (int b = threadIdx.x; b < NBUCK; b += 256) cur[b] = bbase[b] + hist[b * PHB + k];
    __syncthreads();
    int e0 = k * CH, e1 = min(e0 + CH, TE);
    for (int e = e0 + threadIdx.x; e < e1; e += 256) {
        int s, d;
        if (e < NE) { s = ei[e]; d = ei[NE + e]; } else { s = e - NE; d = s; }
        int b = d / DPB, ld = d - b * DPB;
        int pos = atomicAdd(&cur[b], 1);
        pairs[pos] = (s << 9) | ld;
    }
}

__global__ void k_csr(const int* __restrict__ pairs, const int* __restrict__ bbase,
                      int* __restrict__ rowptr, int* __restrict__ colsrc) {
    __shared__ int deg[DPB];
    __shared__ int exc[DPB];
    __shared__ int sc[512];
    int b = blockIdx.x, t = threadIdx.x;
    int base = bbase[b], cnt = bbase[b + 1] - base;
    int d0 = b * DPB;
    int ndst = min(DPB, NN - d0);
    for (int i = t; i < DPB; i += 256) deg[i] = 0;
    __syncthreads();
    for (int i = t; i < cnt; i += 256) atomicAdd(&deg[pairs[base + i] & 511], 1);
    __syncthreads();
    sc[t] = (t < DPB) ? deg[t] : 0;
    sc[t + 256] = (t + 256 < DPB) ? deg[t + 256] : 0;
    __syncthreads();
    for (int off = 1; off < 512; off <<= 1) {
        int a0 = (t >= off) ? sc[t - off] : 0;
        int a1 = (t + 256 >= off) ? sc[t + 256 - off] : 0;
        __syncthreads();
        sc[t] += a0; sc[t + 256] += a1;
        __syncthreads();
    }
    if (t < DPB) exc[t] = sc[t] - deg[t];
    if (t + 256 < DPB) exc[t + 256] = sc[t + 256] - deg[t + 256];
    __syncthreads();
    for (int i = t; i < ndst; i += 256) rowptr[d0 + i] = base + exc[i];
    for (int i = t; i < DPB; i += 256) deg[i] = 0;
    __syncthreads();
    for (int i = t; i < cnt; i += 256) {
        int p = pairs[base + i];
        int ld = p & 511;
        int s = (unsigned)p >> 9;
        int pos = base + exc[ld] + atomicAdd(&deg[ld], 1);
        colsrc[pos] = s;
    }
}

// ---------------- wa precompute: wa[h][i] = sum_c W[i][h*C+c] * a[h][c] ----------------

__global__ void k_wa(const float* __restrict__ W1, const float* __restrict__ as1,
                     const float* __restrict__ ad1,
                     const float* __restrict__ W2, const float* __restrict__ as2,
                     const float* __restrict__ ad2,
                     const float* __restrict__ W3, const float* __restrict__ as3,
                     const float* __restrict__ ad3,
                     float* __restrict__ was1, float* __restrict__ wad1,
                     float* __restrict__ was2, float* __restrict__ wad2,
                     float* __restrict__ was3, float* __restrict__ wad3) {
    int t = threadIdx.x;
    if (t < 6) {         // L1: IN=3, C=16
        int h = t / 3, i = t % 3;
        float s = 0.f, d = 0.f;
        for (int c = 0; c < 16; ++c) {
            float w = W1[i * 32 + h * 16 + c];
            s += w * as1[h * 16 + c];
            d += w * ad1[h * 16 + c];
        }
        was1[t] = s; wad1[t] = d;
    }
    if (t < 64) {        // L2: IN=32, C=32
        int h = t / 32, i = t % 32;
        float s = 0.f, d = 0.f;
        for (int c = 0; c < 32; ++c) {
            float w = W2[i * 64 + h * 32 + c];
            s += w * as2[h * 32 + c];
            d += w * ad2[h * 32 + c];
        }
        was2[t] = s; wad2[t] = d;
    }
    if (t < 128) {       // L3: IN=64, C=64
        int h = t / 64, i = t % 64;
        float s = 0.f, d = 0.f;
        for (int c = 0; c < 64; ++c) {
            float w = W3[i * 128 + h * 64 + c];
            s += w * as3[h * 64 + c];
            d += w * ad3[h * 64 + c];
        }
        was3[t] = s; wad3[t] = d;
    }
}

// ---------------- W split+transpose: Wt_hi/lo[c][i] bf16 (W = hi + lo) ----------------

__global__ void k_wsplit(const float* __restrict__ W2, const float* __restrict__ W3,
                         unsigned short* __restrict__ w2hi, unsigned short* __restrict__ w2lo,
                         unsigned short* __restrict__ w3hi, unsigned short* __restrict__ w3lo) {
    int t = blockIdx.x * 256 + threadIdx.x;
    if (t < 2048) {                       // W2: IN=32, OUT=64; Wt[c][i]
        int c = t / 32, i = t % 32;
        float w = W2[i * 64 + c];
        unsigned short hi = f2bf(w);
        float lo = w - bf2f(hi);
        w2hi[c * 32 + i] = hi;
        w2lo[c * 32 + i] = f2bf(lo);
    }
    if (t < 8192) {                       // W3: IN=64, OUT=128; Wt[c][i]
        int c = t / 64, i = t % 64;
        float w = W3[i * 128 + c];
        unsigned short hi = f2bf(w);
        float lo = w - bf2f(hi);
        w3hi[c * 64 + i] = hi;
        w3lo[c * 64 + i] = f2bf(lo);
    }
}

// ---------------- Logits (layer 1 only: fp32 x, no BN) ----------------

__global__ void k_logits1(const float* __restrict__ x, const float* __restrict__ was,
                          const float* __restrict__ wad, float* __restrict__ als,
                          float* __restrict__ ald) {
    int n = blockIdx.x * 256 + threadIdx.x;
    if (n >= NN) return;
    float x0 = x[n * 3], x1 = x[n * 3 + 1], x2 = x[n * 3 + 2];
    als[n * 2 + 0] = x0 * was[0] + x1 * was[1] + x2 * was[2];
    als[n * 2 + 1] = x0 * was[3] + x1 * was[4] + x2 * was[5];
    ald[n * 2 + 0] = x0 * wad[0] + x1 * wad[1] + x2 * wad[2];
    ald[n * 2 + 1] = x0 * wad[3] + x1 * wad[4] + x2 * wad[5];
}

// ---------------- Prep: fused BN-apply + ReLU + logits ----------------

template <int IN>
__global__ void k_prep(const unsigned short* __restrict__ x,
                       const float* __restrict__ bnrep,
                       const float* __restrict__ gamma, const float* __restrict__ beta,
                       const float* __restrict__ was, const float* __restrict__ wad,
                       unsigned short* __restrict__ xbn,
                       float* __restrict__ als, float* __restrict__ ald) {
    constexpr int P = IN / 8;   // lanes per node (16B each)
    __shared__ float sbn[2 * IN];
    __shared__ float swa[4 * IN];
    if (threadIdx.x < IN) {
        int c = threadIdx.x;
        float s = 0.f, ss = 0.f;
#pragma unroll
        for (int r = 0; r < NREP; ++r) {
            s  += bnrep[r * 2 * IN + c];
            ss += bnrep[r * 2 * IN + IN + c];
        }
        float mu = s / NN;
        float var = ss / NN - mu * mu;
        float sca = gamma[c] * rsqrtf(var + EPS);
        sbn[c] = sca;
        sbn[IN + c] = beta[c] - mu * sca;
    }
    for (int i = threadIdx.x; i < 2 * IN; i += 256) {
        swa[i] = was[i];
        swa[2 * IN + i] = wad[i];
    }
    __syncthreads();
    int idx = blockIdx.x * 256 + threadIdx.x;
    int node = idx / P, pl = idx % P;
    if (node >= NN) return;
    uint4 v = *(const uint4*)&x[(size_t)node * IN + pl * 8];
    float f[8];
    unpack8(v, f);
    float s0 = 0.f, s1 = 0.f, d0 = 0.f, d1 = 0.f;
#pragma unroll
    for (int k = 0; k < 8; ++k) {
        int c = pl * 8 + k;
        float t = f[k] * sbn[c] + sbn[IN + c];
        t = t > 0.f ? t : 0.f;
        f[k] = t;
        s0 += t * swa[c];           s1 += t * swa[IN + c];
        d0 += t * swa[2 * IN + c];  d1 += t * swa[3 * IN + c];
    }
    *(uint4*)&xbn[(size_t)node * IN + pl * 8] = pack8(f);
#pragma unroll
    for (int m = 1; m < P; m <<= 1) {
        s0 += __shfl_xor(s0, m, 64); s1 += __shfl_xor(s1, m, 64);
        d0 += __shfl_xor(d0, m, 64); d1 += __shfl_xor(d1, m, 64);
    }
    if (pl == 0) {
        als[node * 2 + 0] = s0; als[node * 2 + 1] = s1;
        ald[node * 2 + 0] = d0; ald[node * 2 + 1] = d1;
    }
}

// ---------------- Alpha: normalized softmax weights per edge, both heads ----------------

__global__ void k_alpha(const int* __restrict__ rowptr, const int* __restrict__ colsrc,
                        const float* __restrict__ als, const float* __restrict__ ald,
                        float2* __restrict__ alf) {
    int wv = threadIdx.x >> 6, lane = threadIdx.x & 63;
    int hw = lane >> 5, hl = lane & 31;
    int base = ((int)blockIdx.x * 4 + wv) * 2;
    int wid = base + hw;
    bool valid = wid < NN;
    int start = 0, cnt = 0;
    float2 dv = make_float2(0.f, 0.f);
    if (valid) {
        start = rowptr[wid];
        cnt = rowptr[wid + 1] - start;
        dv = ((const float2*)ald)[wid];
    }
    int mc = max(cnt, __shfl_xor(cnt, 32, 64));

    if (mc <= 32) {
        int e = start + hl;
        bool act = valid && (hl < cnt);
        int s = act ? colsrc[e] : 0;
        float2 av = act ? ((const float2*)als)[s] : make_float2(0.f, 0.f);
        float t0 = act ? lrelu(av.x + dv.x) : -1e30f;
        float t1 = act ? lrelu(av.y + dv.y) : -1e30f;
        float m0 = t0, m1 = t1;
#pragma unroll
        for (int off = 16; off; off >>= 1) {
            m0 = fmaxf(m0, __shfl_xor(m0, off, 32));
            m1 = fmaxf(m1, __shfl_xor(m1, off, 32));
        }
        float w0 = act ? __expf(t0 - m0) : 0.f;
        float w1 = act ? __expf(t1 - m1) : 0.f;
        float den0 = w0, den1 = w1;
#pragma unroll
        for (int off = 16; off; off >>= 1) {
            den0 += __shfl_xor(den0, off, 32);
            den1 += __shfl_xor(den1, off, 32);
        }
        if (act) alf[e] = make_float2(w0 / den0, w1 / den1);
    } else {
        // rare fallback: whole wave per node
        for (int i2 = 0; i2 < 2; ++i2) {
            int w2 = base + i2;
            if (w2 >= NN) continue;
            int st = rowptr[w2], en = rowptr[w2 + 1];
            float2 dv2 = ((const float2*)ald)[w2];
            float m0 = -1e30f, m1 = -1e30f;
            for (int e = st + lane; e < en; e += 64) {
                int s = colsrc[e];
                m0 = fmaxf(m0, lrelu(als[s * 2 + 0] + dv2.x));
                m1 = fmaxf(m1, lrelu(als[s * 2 + 1] + dv2.y));
            }
#pragma unroll
            for (int off = 32; off; off >>= 1) {
                m0 = fmaxf(m0, __shfl_xor(m0, off, 64));
                m1 = fmaxf(m1, __shfl_xor(m1, off, 64));
            }
            float den0 = 0.f, den1 = 0.f;
            for (int e = st + lane; e < en; e += 64) {
                int s = colsrc[e];
                den0 += __expf(lrelu(als[s * 2 + 0] + dv2.x) - m0);
                den1 += __expf(lrelu(als[s * 2 + 1] + dv2.y) - m1);
            }
#pragma unroll
            for (int off = 32; off; off >>= 1) {
                den0 += __shfl_xor(den0, off, 64);
                den1 += __shfl_xor(den1, off, 64);
            }
            float inv0 = 1.f / den0, inv1 = 1.f / den1;
            for (int e = st + lane; e < en; e += 64) {
                int s = colsrc[e];
                alf[e] = make_float2(__expf(lrelu(als[s * 2 + 0] + dv2.x) - m0) * inv0,
                                     __expf(lrelu(als[s * 2 + 1] + dv2.y) - m1) * inv1);
            }
        }
    }
}

// ---------------- Gather: agg[dst][head][i] = sum alpha_e xbn[src][i] ----------------

template <int IN>
__global__ void k_gather(const int* __restrict__ rowptr, const int* __restrict__ colsrc,
                         const float2* __restrict__ alf,
                         const unsigned short* __restrict__ x,
                         unsigned short* __restrict__ agg) {
    constexpr int LPE = IN / 8;     // lanes per edge (16B each)
    constexpr int EPI2 = 32 / LPE;  // edge slots per iter per half-wave
    constexpr int UNR = 2;
    int wv = threadIdx.x >> 6, lane = threadIdx.x & 63;
    int hw = lane >> 5, hl = lane & 31;
    int wid = ((int)blockIdx.x * 4 + wv) * 2 + hw;
    if (wid >= NN) return;
    int start = rowptr[wid];
    int cnt = rowptr[wid + 1] - start;
    int sub = hl / LPE, cl = hl % LPE;
    float a0[8], a1[8];
#pragma unroll
    for (int k = 0; k < 8; ++k) { a0[k] = 0.f; a1[k] = 0.f; }
    int cm1 = cnt - 1;
    for (int j0 = 0; j0 < cnt; j0 += EPI2 * UNR) {
        float l0[UNR], l1[UNR];
        uint4 hv[UNR];
#pragma unroll
        for (int u = 0; u < UNR; ++u) {
            int jj = j0 + u * EPI2 + sub;
            int jc = min(jj, cm1);
            int e = start + jc;
            int s = colsrc[e];
            float2 al = alf[e];
            bool on = jj <= cm1;
            l0[u] = on ? al.x : 0.f;
            l1[u] = on ? al.y : 0.f;
            hv[u] = *(const uint4*)&x[(size_t)s * IN + cl * 8];
        }
#pragma unroll
        for (int u = 0; u < UNR; ++u) {
            float f[8];
            unpack8(hv[u], f);
#pragma unroll
            for (int k = 0; k < 8; ++k) {
                a0[k] += l0[u] * f[k];
                a1[k] += l1[u] * f[k];
            }
        }
    }
#pragma unroll
    for (int m = LPE; m < 32; m <<= 1) {
#pragma unroll
        for (int k = 0; k < 8; ++k) {
            a0[k] += __shfl_xor(a0[k], m, 64);
            a1[k] += __shfl_xor(a1[k], m, 64);
        }
    }
    if (sub == 0) {
        *(uint4*)&agg[(size_t)wid * 2 * IN + cl * 8] = pack8(a0);
        *(uint4*)&agg[(size_t)wid * 2 * IN + IN + cl * 8] = pack8(a1);
    }
}

// Layer-1 aggregate: x fp32 [NN][3] (1.2 MB, L2-resident); agg fp32 [NN][6].
__global__ void k_agg1(const int* __restrict__ rowptr, const int* __restrict__ colsrc,
                       const float* __restrict__ x, const float* __restrict__ als,
                       const float* __restrict__ ald, float* __restrict__ agg) {
    int wv = threadIdx.x >> 6, lane = threadIdx.x & 63;
    int hw = lane >> 5, hl = lane & 31;
    int base = ((int)blockIdx.x * 4 + wv) * 2;
    int wid = base + hw;
    bool valid = wid < NN;
    int start = 0, cnt = 0;
    float2 dv = make_float2(0.f, 0.f);
    if (valid) {
        start = rowptr[wid];
        cnt = rowptr[wid + 1] - start;
        dv = ((const float2*)ald)[wid];
    }
    int mc = max(cnt, __shfl_xor(cnt, 32, 64));
    if (mc <= 32) {
        int e = start + hl;
        bool act = valid && (hl < cnt);
        int s = act ? colsrc[e] : 0;
        float2 av = act ? ((const float2*)als)[s] : make_float2(0.f, 0.f);
        float t0 = act ? lrelu(av.x + dv.x) : -1e30f;
        float t1 = act ? lrelu(av.y + dv.y) : -1e30f;
        float m0 = t0, m1 = t1;
#pragma unroll
        for (int off = 16; off; off >>= 1) {
            m0 = fmaxf(m0, __shfl_xor(m0, off, 32));
            m1 = fmaxf(m1, __shfl_xor(m1, off, 32));
        }
        float w0 = act ? __expf(t0 - m0) : 0.f;
        float w1 = act ? __expf(t1 - m1) : 0.f;
        float den0 = w0, den1 = w1;
#pragma unroll
        for (int off = 16; off; off >>= 1) {
            den0 += __shfl_xor(den0, off, 32);
            den1 += __shfl_xor(den1, off, 32);
        }
        float a[6];
#pragma unroll
        for (int k = 0; k < 6; ++k) a[k] = 0.f;
        if (act) {
            float al0 = w0 / den0, al1 = w1 / den1;
            float x0 = x[s * 3], x1 = x[s * 3 + 1], x2 = x[s * 3 + 2];
            a[0] = al0 * x0; a[1] = al0 * x1; a[2] = al0 * x2;
            a[3] = al1 * x0; a[4] = al1 * x1; a[5] = al1 * x2;
        }
#pragma unroll
        for (int m = 1; m < 32; m <<= 1) {
#pragma unroll
            for (int k = 0; k < 6; ++k) a[k] += __shfl_xor(a[k], m, 64);
        }
        if (valid && hl == 0) {
#pragma unroll
            for (int k = 0; k < 6; ++k) agg[(size_t)wid * 6 + k] = a[k];
        }
    } else {
        for (int i2 = 0; i2 < 2; ++i2) {
            int w2 = base + i2;
            if (w2 >= NN) continue;
            int st = rowptr[w2], en = rowptr[w2 + 1];
            float2 dv2 = ((const float2*)ald)[w2];
            float m0 = -1e30f, m1 = -1e30f;
            for (int e = st + lane; e < en; e += 64) {
                int s = colsrc[e];
                m0 = fmaxf(m0, lrelu(als[s * 2 + 0] + dv2.x));
                m1 = fmaxf(m1, lrelu(als[s * 2 + 1] + dv2.y));
            }
#pragma unroll
            for (int off = 32; off; off >>= 1) {
                m0 = fmaxf(m0, __shfl_xor(m0, off, 64));
                m1 = fmaxf(m1, __shfl_xor(m1, off, 64));
            }
            float den0 = 0.f, den1 = 0.f;
            for (int e = st + lane; e < en; e += 64) {
                int s = colsrc[e];
                den0 += __expf(lrelu(als[s * 2 + 0] + dv2.x) - m0);
                den1 += __expf(lrelu(als[s * 2 + 1] + dv2.y) - m1);
            }
#pragma unroll
            for (int off = 32; off; off >>= 1) {
                den0 += __shfl_xor(den0, off, 64);
                den1 += __shfl_xor(den1, off, 64);
            }
            float inv0 = 1.f / den0, inv1 = 1.f / den1;
            float a[6];
#pragma unroll
            for (int k = 0; k < 6; ++k) a[k] = 0.f;
            for (int e = st + lane; e < en; e += 64) {
                int s = colsrc[e];
                float aa0 = __expf(lrelu(als[s * 2 + 0] + dv2.x) - m0) * inv0;
                float aa1 = __expf(lrelu(als[s * 2 + 1] + dv2.y) - m1) * inv1;
                float x0 = x[s * 3], x1 = x[s * 3 + 1], x2 = x[s * 3 + 2];
                a[0] += aa0 * x0; a[1] += aa0 * x1; a[2] += aa0 * x2;
                a[3] += aa1 * x0; a[4] += aa1 * x1; a[5] += aa1 * x2;
            }
#pragma unroll
            for (int m = 1; m < 64; m <<= 1) {
#pragma unroll
                for (int k = 0; k < 6; ++k) a[k] += __shfl_xor(a[k], m, 64);
            }
            if (lane == 0) {
#pragma unroll
                for (int k = 0; k < 6; ++k) agg[(size_t)w2 * 6 + k] = a[k];
            }
        }
    }
}

// ---------------- MFMA transform (per-head GEMM, error-split bf16 W) ----------------
// OPERANDS SWAPPED vs R19: mfma(W-frag, agg-frag) -> D row=channel, col=node.
// Each lane then owns 4 CONSECUTIVE channels of ONE node per tile -> one 8B
// uint2 store (4x fewer store instrs, 32B dense per 4-lane group). BN sums
// reduce over the 16 lr-lanes via shfl (VALU idle), 4 lanes/wave do
// conflict-free LDS atomics.

template <int IN, int OUT>
__global__ void k_tmfma(const unsigned short* __restrict__ agg,
                        const unsigned short* __restrict__ whi,
                        const unsigned short* __restrict__ wlo,
                        unsigned short* __restrict__ xout,
                        float* __restrict__ bnrep) {
    constexpr int C = OUT / 2;
    constexpr int NT = C / 16;      // n-tiles per head
    constexpr int KS = IN / 32;     // k-steps
    __shared__ float red[2 * OUT];
    for (int i = threadIdx.x; i < 2 * OUT; i += 256) red[i] = 0.f;
    __syncthreads();
    int wv = threadIdx.x >> 6, l = threadIdx.x & 63;
    int head = wv & 1;
    int node0 = blockIdx.x * 32 + (wv >> 1) * 16;
    int lr = l & 15, kg = l >> 4;
    // B operand (agg): col=lr -> node, k = kg*8+j
    bf16x8 a[KS];
#pragma unroll
    for (int ks = 0; ks < KS; ++ks)
        a[ks] = ld_bf8(&agg[(size_t)(node0 + lr) * 2 * IN + head * IN + ks * 32 + kg * 8]);
    f32x4 acc[NT];
#pragma unroll
    for (int nt = 0; nt < NT; ++nt) acc[nt] = (f32x4){0.f, 0.f, 0.f, 0.f};
#pragma unroll
    for (int nt = 0; nt < NT; ++nt) {
        int ch = head * C + nt * 16 + lr;          // A row (channel) for this lane
#pragma unroll
        for (int ks = 0; ks < KS; ++ks) {
            bf16x8 bh = ld_bf8(&whi[(size_t)ch * IN + ks * 32 + kg * 8]);
            bf16x8 bl = ld_bf8(&wlo[(size_t)ch * IN + ks * 32 + kg * 8]);
            acc[nt] = __builtin_amdgcn_mfma_f32_16x16x32_bf16(bh, a[ks], acc[nt], 0, 0, 0);
            acc[nt] = __builtin_amdgcn_mfma_f32_16x16x32_bf16(bl, a[ks], acc[nt], 0, 0, 0);
        }
    }
    // epilogue: D col = lr (node), row = kg*4 + r (channel within tile)
    int node = node0 + lr;
#pragma unroll
    for (int nt = 0; nt < NT; ++nt) {
        int chB = head * C + nt * 16 + kg * 4;      // 4 consecutive channels
        float v0 = acc[nt][0], v1 = acc[nt][1], v2 = acc[nt][2], v3 = acc[nt][3];
        uint2 pk;
        pk.x = (unsigned)f2bf(v0) | ((unsigned)f2bf(v1) << 16);
        pk.y = (unsigned)f2bf(v2) | ((unsigned)f2bf(v3) << 16);
        *(uint2*)&xout[(size_t)node * OUT + chB] = pk;
        float s0 = v0, s1 = v1, s2 = v2, s3 = v3;
        float q0 = v0 * v0, q1 = v1 * v1, q2 = v2 * v2, q3 = v3 * v3;
#pragma unroll
        for (int m = 1; m < 16; m <<= 1) {
            s0 += __shfl_xor(s0, m, 64); s1 += __shfl_xor(s1, m, 64);
            s2 += __shfl_xor(s2, m, 64); s3 += __shfl_xor(s3, m, 64);
            q0 += __shfl_xor(q0, m, 64); q1 += __shfl_xor(q1, m, 64);
            q2 += __shfl_xor(q2, m, 64); q3 += __shfl_xor(q3, m, 64);
        }
        if (lr == 0) {
            atomicAdd(&red[chB + 0], s0); atomicAdd(&red[OUT + chB + 0], q0);
            atomicAdd(&red[chB + 1], s1); atomicAdd(&red[OUT + chB + 1], q1);
            atomicAdd(&red[chB + 2], s2); atomicAdd(&red[OUT + chB + 2], q2);
            atomicAdd(&red[chB + 3], s3); atomicAdd(&red[OUT + chB + 3], q3);
        }
    }
    __syncthreads();
    float* dst = &bnrep[(blockIdx.x & (NREP - 1)) * 2 * OUT];
    for (int i = threadIdx.x; i < 2 * OUT; i += 256) atomicAdd(&dst[i], red[i]);
}

// Layer-1 transform: agg fp32 [NN][6] -> out [NN][32] bf16 + BN1 partials.
__global__ void k_transform1(const float* __restrict__ agg, const float* __restrict__ W,
                             unsigned short* __restrict__ xout, float* __restrict__ bnrep,
                             int n) {
    __shared__ float xs[32 * 7];     // padded node stride 7 (6 used)
    __shared__ float red[64];
    for (int i = threadIdx.x; i < 64; i += 256) red[i] = 0.f;
    int node0 = blockIdx.x * 32;
    for (int i = threadIdx.x; i < 192; i += 256) {
        int nn = node0 + i / 6;
        float v = (nn < n) ? agg[(size_t)node0 * 6 + i] : 0.f;
        xs[(i / 6) * 7 + (i % 6)] = v;
    }
    __syncthreads();
    int nl = threadIdx.x / 8, q = threadIdx.x % 8;
    int hd = (q >= 4);
    int node = node0 + nl;
    float4 acc = {0.f, 0.f, 0.f, 0.f};
#pragma unroll
    for (int i = 0; i < 3; ++i) {
        float xv = xs[nl * 7 + hd * 3 + i];
        float4 w = *(const float4*)&W[i * 32 + q * 4];
        acc.x += xv * w.x; acc.y += xv * w.y; acc.z += xv * w.z; acc.w += xv * w.w;
    }
    __syncthreads();
    if (node < n) {
        uint2 pk;
        pk.x = (unsigned)f2bf(acc.x) | ((unsigned)f2bf(acc.y) << 16);
        pk.y = (unsigned)f2bf(acc.z) | ((unsigned)f2bf(acc.w) << 16);
        *(uint2*)&xout[(size_t)node * 32 + q * 4] = pk;
        atomicAdd(&red[q * 4 + 0], acc.x); atomicAdd(&red[32 + q * 4 + 0], acc.x * acc.x);
        atomicAdd(&red[q * 4 + 1], acc.y); atomicAdd(&red[32 + q * 4 + 1], acc.y * acc.y);
        atomicAdd(&red[q * 4 + 2], acc.z); atomicAdd(&red[32 + q * 4 + 2], acc.z * acc.z);
        atomicAdd(&red[q * 4 + 3], acc.w); atomicAdd(&red[32 + q * 4 + 3], acc.w * acc.w);
    }
    __syncthreads();
    float* dst = &bnrep[(blockIdx.x & (NREP - 1)) * 64];
    for (int i = threadIdx.x; i < 64; i += 256) atomicAdd(&dst[i], red[i]);
}

// ---------------- Pooling (BN3 inline + ReLU) + FC ----------------

__global__ void k_pool(const unsigned short* __restrict__ h, const int* __restrict__ batch,
                       const float* __restrict__ bnrep, const float* __restrict__ gamma,
                       const float* __restrict__ beta, float* __restrict__ pooled, int n) {
    const int K = 32;
    int c = threadIdx.x;
    float s = 0.f, ss = 0.f;
#pragma unroll
    for (int r = 0; r < NREP; ++r) {
        s  += bnrep[r * 256 + c];
        ss += bnrep[r * 256 + 128 + c];
    }
    float mu = s / n;
    float var = ss / n - mu * mu;
    float scale = gamma[c] * rsqrtf(var + EPS);
    float shift = beta[c] - mu * scale;
    int n0 = blockIdx.x * K;
    if (n0 >= n) return;
    int nend = min(n, n0 + K);
    int curg = batch[n0];
    float m = 0.f;
    for (int nn = n0; nn < nend; ++nn) {
        int g = batch[nn];
        if (g != curg) {
            atomicMax((int*)&pooled[curg * 128 + c], __float_as_int(m));
            m = 0.f; curg = g;
        }
        float v = bf2f(h[(size_t)nn * 128 + c]) * scale + shift;
        m = fmaxf(m, v > 0.f ? v : 0.f);
    }
    atomicMax((int*)&pooled[curg * 128 + c], __float_as_int(m));
}

__global__ void k_fc(const float* __restrict__ pooled, const float* __restrict__ fcw,
                     const float* __restrict__ fcb, float* __restrict__ out) {
    int t = threadIdx.x;
    if (t >= NG * 10) return;
    int g = t / 10, j = t % 10;
    float acc = fcb[j];
#pragma unroll
    for (int c = 0; c < 128; ++c) acc += pooled[g * 128 + c] * fcw[c * 10 + j];
    out[g * 10 + j] = acc;
}

// ---------------- Host launch ----------------

extern "C" void kernel_launch(void* const* d_in, const int* in_sizes, int n_in,
                              void* d_out, int out_size, void* d_ws, size_t ws_size,
                              hipStream_t stream) {
    const float* x   = (const float*)d_in[0];
    const int*   ei  = (const int*)d_in[1];
    const int*   bat = (const int*)d_in[2];
    const float* W1  = (const float*)d_in[3];
    const float* as1 = (const float*)d_in[4];
    const float* ad1 = (const float*)d_in[5];
    // d_in[6] = b1 (cancels under BN)
    const float* g1  = (const float*)d_in[7];
    const float* be1 = (const float*)d_in[8];
    const float* W2  = (const float*)d_in[9];
    const float* as2 = (const float*)d_in[10];
    const float* ad2 = (const float*)d_in[11];
    const float* g2  = (const float*)d_in[13];
    const float* be2 = (const float*)d_in[14];
    const float* W3  = (const float*)d_in[15];
    const float* as3 = (const float*)d_in[16];
    const float* ad3 = (const float*)d_in[17];
    const float* g3  = (const float*)d_in[19];
    const float* be3 = (const float*)d_in[20];
    const float* fcw = (const float*)d_in[21];
    const float* fcb = (const float*)d_in[22];
    float* out = (float*)d_out;

    char* w = (char*)d_ws;
    size_t off = 0;
    auto take = [&](size_t bytes) {
        void* p = w + off;
        off += (bytes + 255) & ~(size_t)255;
        return p;
    };
    // ---- single zero-init region: bnrep1/2/3 | pooled ----
    constexpr size_t ZN = (size_t)NREP * 2 * (32 + 64 + 128) + NG * 128;
    char* zreg = (char*)take(ZN * 4);
    float* bnr1   = (float*)zreg;                    // NREP*64
    float* bnr2   = bnr1 + NREP * 64;                // NREP*128
    float* bnr3   = bnr2 + NREP * 128;               // NREP*256
    float* pooled = bnr3 + NREP * 256;               // NG*128

    int*   hist    = (int*)take((size_t)NBUCK * PHB * 4);
    int*   bsum    = (int*)take(NBUCK * 4);
    int*   bbase   = (int*)take((NBUCK + 1) * 4);
    int*   rowptr  = (int*)take((size_t)(NN + 1) * 4);
    int*   pairs   = (int*)take((size_t)TE * 4);
    int*   colsrc  = (int*)take((size_t)TE * 4);
    float* al_s    = (float*)take((size_t)NN * 2 * 4);
    float* al_d    = (float*)take((size_t)NN * 2 * 4);
    float2* alf    = (float2*)take((size_t)TE * 8);
    float* was1    = (float*)take(64);
    float* wad1    = (float*)take(64);
    float* was2    = (float*)take(64 * 4);
    float* wad2    = (float*)take(64 * 4);
    float* was3    = (float*)take(128 * 4);
    float* wad3    = (float*)take(128 * 4);
    unsigned short* w2hi = (unsigned short*)take(2048 * 2);
    unsigned short* w2lo = (unsigned short*)take(2048 * 2);
    unsigned short* w3hi = (unsigned short*)take(8192 * 2);
    unsigned short* w3lo = (unsigned short*)take(8192 * 2);
    float* agg1f   = (float*)take((size_t)NN * 6 * 4);                  // fp32 [NN][6]
    unsigned short* aggb = (unsigned short*)take((size_t)NN * 128 * 2); // bf16 [NN][2*IN]
    unsigned short* x2   = (unsigned short*)take((size_t)NN * 32 * 2);  // pre-BN
    unsigned short* xbn2 = (unsigned short*)take((size_t)NN * 32 * 2);  // post-BN-ReLU
    unsigned short* x3   = (unsigned short*)take((size_t)NN * 64 * 2);
    unsigned short* xbn3 = (unsigned short*)take((size_t)NN * 64 * 2);
    unsigned short* x4   = (unsigned short*)take((size_t)NN * 128 * 2);

    hipMemsetAsync(zreg, 0, ZN * 4, stream);

    // ---- CSR build (bucketed counting sort) ----
    k_hist<<<PHB, 256, 0, stream>>>(ei, hist);
    k_scanA<<<NBUCK, PHB, 0, stream>>>(hist, bsum);
    k_scanB<<<1, NBUCK, 0, stream>>>(bsum, bbase, rowptr);
    k_scatter<<<PHB, 256, 0, stream>>>(ei, hist, bbase, pairs);
    k_csr<<<NBUCK, 256, 0, stream>>>(pairs, bbase, rowptr, colsrc);

    k_wa<<<1, 256, 0, stream>>>(W1, as1, ad1, W2, as2, ad2, W3, as3, ad3,
                                was1, wad1, was2, wad2, was3, wad3);
    k_wsplit<<<32, 256, 0, stream>>>(W2, W3, w2hi, w2lo, w3hi, w3lo);

    const int AGG_BLOCKS = (NN + 7) / 8;   // 4 waves/block, 2 nodes/wave

    // ---- layer 1: 3 -> 32 ----
    k_logits1<<<(NN + 255) / 256, 256, 0, stream>>>(x, was1, wad1, al_s, al_d);
    k_agg1<<<AGG_BLOCKS, 256, 0, stream>>>(rowptr, colsrc, x, al_s, al_d, agg1f);
    k_transform1<<<(NN + 31) / 32, 256, 0, stream>>>(agg1f, W1, x2, bnr1, NN);

    // ---- layer 2: 32 -> 64 ----
    k_prep<32><<<(NN * 4 + 255) / 256, 256, 0, stream>>>(x2, bnr1, g1, be1, was2, wad2,
                                                         xbn2, al_s, al_d);
    k_alpha<<<AGG_BLOCKS, 256, 0, stream>>>(rowptr, colsrc, al_s, al_d, alf);
    k_gather<32><<<AGG_BLOCKS, 256, 0, stream>>>(rowptr, colsrc, alf, xbn2, aggb);
    k_tmfma<32, 64><<<NN / 32, 256, 0, stream>>>(aggb, w2hi, w2lo, x3, bnr2);

    // ---- layer 3: 64 -> 128 ----
    k_prep<64><<<(NN * 8 + 255) / 256, 256, 0, stream>>>(x3, bnr2, g2, be2, was3, wad3,
                                                         xbn3, al_s, al_d);
    k_alpha<<<AGG_BLOCKS, 256, 0, stream>>>(rowptr, colsrc, al_s, al_d, alf);
    k_gather<64><<<AGG_BLOCKS, 256, 0, stream>>>(rowptr, colsrc, alf, xbn3, aggb);
    k_tmfma<64, 128><<<NN / 32, 256, 0, stream>>>(aggb, w3hi, w3lo, x4, bnr3);

    // ---- pool (BN3 inline) + fc ----
    k_pool<<<(NN + 31) / 32, 128, 0, stream>>>(x4, bat, bnr3, g3, be3, pooled, NN);
    k_fc<<<1, 640, 0, stream>>>(pooled, fcw, fcb, out);
}